// Round 8
// baseline (538.179 us; speedup 1.0000x reference)
//
#include <hip/hip_runtime.h>
#include <stdint.h>

typedef short bf8 __attribute__((ext_vector_type(8)));   // 8 bf16 in 4 VGPR
typedef short s4v __attribute__((ext_vector_type(4)));   // 4 bf16 = 8B
typedef float f32x4 __attribute__((ext_vector_type(4)));

#define VM_WAIT(N) asm volatile("s_waitcnt vmcnt(" #N ")" ::: "memory")
#define LGKM0()    asm volatile("s_waitcnt lgkmcnt(0)" ::: "memory")
#define SBAR()     do { __builtin_amdgcn_sched_barrier(0); __builtin_amdgcn_s_barrier(); \
                        __builtin_amdgcn_sched_barrier(0); } while (0)

__device__ __forceinline__ short f2bf(float f){
  union { float f; unsigned u; } c; c.f = f;
  unsigned r = (c.u + 0x7fffu + ((c.u >> 16) & 1u)) >> 16;
  return (short)r;
}
__device__ __forceinline__ float bf2f(short s){
  union { unsigned u; float f; } c; c.u = ((unsigned)(unsigned short)s) << 16;
  return c.f;
}
__device__ __forceinline__ void gload16(const void* g, void* l){
  __builtin_amdgcn_global_load_lds((const __attribute__((address_space(1))) uint32_t*)g,
                                   (__attribute__((address_space(3))) uint32_t*)l, 16, 0, 0);
}
// Fast erf: Abramowitz-Stegun 7.1.26, |err| <= 1.5e-7, branchless ~14 VALU inst.
__device__ __forceinline__ float fast_erf(float x){
  const float s = fabsf(x);
  const float t = __builtin_amdgcn_rcpf(fmaf(0.3275911f, s, 1.0f));
  float p = fmaf(1.061405429f, t, -1.453152027f);
  p = fmaf(p, t, 1.421413741f);
  p = fmaf(p, t, -0.284496736f);
  p = fmaf(p, t, 0.254829592f);
  p = p * t;
  const float e = __expf(-s * s);
  return copysignf(fmaf(-p, e, 1.0f), x);
}
__device__ __forceinline__ float act_gelu(float x){
  return 0.5f * x * (1.0f + fast_erf(x * 0.70710678118654752f));
}
__device__ __forceinline__ float act_softplus(float x){
  const float e = __expf(-fabsf(x));
  return fmaxf(x, 0.0f) + __logf(1.0f + e);
}

// ---- stats + transpose: read x (B,C,N) f32 once; write xt (B,N,C) bf16 (UNnormalized)
//      and per-(b,c) partial sums over each 64-px tile. Norm is folded into weights. ----
__global__ __launch_bounds__(256) void k_statst(const float* __restrict__ x, short* __restrict__ xt,
                                                float* __restrict__ ps1, float* __restrict__ ps2){
  const int n0 = blockIdx.x * 64, c0 = blockIdx.y * 64, b = blockIdx.z;
  __shared__ short lt[64][68];
  const int t = threadIdx.x, nj = (t & 15) * 4, cb = t >> 4;
  float s1[4] = {0.f,0.f,0.f,0.f}, s2[4] = {0.f,0.f,0.f,0.f};
#pragma unroll
  for (int it = 0; it < 4; ++it){
    const int ci = cb + it * 16;
    const int row = b * 256 + c0 + ci;
    float4 v = *(const float4*)(x + (size_t)row * 16384 + n0 + nj);
    s4v o;
    o[0] = f2bf(v.x); o[1] = f2bf(v.y); o[2] = f2bf(v.z); o[3] = f2bf(v.w);
    *(s4v*)(&lt[ci][nj]) = o;
    s1[it] += v.x + v.y + v.z + v.w;
    s2[it] += v.x*v.x + v.y*v.y + v.z*v.z + v.w*v.w;
  }
  __syncthreads();
#pragma unroll
  for (int p = 0; p < 2; ++p){
    const int q = p * 256 + t;
    const int nl = q >> 3, c8 = (q & 7) * 8;
    bf8 o;
#pragma unroll
    for (int j = 0; j < 8; ++j) o[j] = lt[c8 + j][nl];
    *(bf8*)(xt + ((size_t)(b * 16384 + n0 + nl)) * 256 + c0 + c8) = o;
  }
#pragma unroll
  for (int it = 0; it < 4; ++it){
#pragma unroll
    for (int off = 8; off > 0; off >>= 1){
      s1[it] += __shfl_down(s1[it], off);
      s2[it] += __shfl_down(s2[it], off);
    }
  }
  if ((t & 15) == 0){
#pragma unroll
    for (int it = 0; it < 4; ++it){
      const int c = c0 + cb + it * 16;
      ps1[((size_t)(b * 256 + c)) * 256 + blockIdx.x] = s1[it];
      ps2[((size_t)(b * 256 + c)) * 256 + blockIdx.x] = s2[it];
    }
  }
}

// ---- reduce 256 tile-partials -> mu, rsig per (b,c) ----
__global__ __launch_bounds__(256) void k_red(const float* __restrict__ ps1, const float* __restrict__ ps2,
                                             float* __restrict__ mu, float* __restrict__ rsig){
  const int bc = blockIdx.x;
  const int t = threadIdx.x;
  __shared__ float a1[256], a2[256];
  a1[t] = ps1[(size_t)bc * 256 + t];
  a2[t] = ps2[(size_t)bc * 256 + t];
  __syncthreads();
  for (int s = 128; s > 0; s >>= 1){
    if (t < s){ a1[t] += a1[t+s]; a2[t] += a2[t+s]; }
    __syncthreads();
  }
  if (t == 0){
    float m = a1[0] * (1.0f/16384.0f);
    float v = a2[0] * (1.0f/16384.0f) - m*m;
    mu[bc] = m; rsig[bc] = rsqrtf(v + 1e-5f);
  }
}

// ---- fold instance-norm into first-layer weights, per batch:
//      W'[b][o][c] = bf16(W[o][c]*rsig[b][c]);  b'[b][o] = b[o] - sum_c W[o][c]*mu[b][c]*rsig[b][c]
__global__ __launch_bounds__(256) void k_wfold(
    const float* __restrict__ w0, const float* __restrict__ bb0,
    const float* __restrict__ w1, const float* __restrict__ bb1,
    const float* __restrict__ w2, const float* __restrict__ bb2,
    const float* __restrict__ w3, const float* __restrict__ bb3,
    const float* __restrict__ mu, const float* __restrict__ rsig,
    short* __restrict__ wf, float* __restrict__ bf){
  const int m = blockIdx.x >> 3, b = blockIdx.x & 7;
  const float* Wm = (m==0)?w0:(m==1)?w1:(m==2)?w2:w3;
  const float* Bm = (m==0)?bb0:(m==1)?bb1:(m==2)?bb2:bb3;
  __shared__ float rs[256], ms[256];
  const int t = threadIdx.x;
  rs[t] = rsig[b*256+t];
  ms[t] = mu[b*256+t] * rs[t];
  __syncthreads();
  short* wout = wf + ((size_t)(m*8+b)) * 65536;
  float* bout = bf + (m*8+b) * 256;
  const int lane = t & 63, wv = t >> 6;
  for (int oi = 0; oi < 64; ++oi){
    const int o = oi * 4 + wv;
    const int c = lane * 4;
    float4 w4 = *(const float4*)(Wm + (size_t)o * 256 + c);
    float pa = w4.x*ms[c] + w4.y*ms[c+1] + w4.z*ms[c+2] + w4.w*ms[c+3];
    s4v o4;
    o4[0] = f2bf(w4.x*rs[c]);   o4[1] = f2bf(w4.y*rs[c+1]);
    o4[2] = f2bf(w4.z*rs[c+2]); o4[3] = f2bf(w4.w*rs[c+3]);
    *(s4v*)(wout + (size_t)o * 256 + c) = o4;
#pragma unroll
    for (int off = 32; off > 0; off >>= 1) pa += __shfl_down(pa, off);
    if (lane == 0) bout[o] = Bm[o] - pa;
  }
}

// ------------- fp32->bf16 weight conversion (3 matrices: Wq2, Wk2, Wo) -------------
__global__ __launch_bounds__(256) void k_wconv(const float* w0, const float* w1, const float* w2,
                                               short* __restrict__ wb){
  const int gid = blockIdx.x * 256 + threadIdx.x;  // 0..49151 float4 chunks
  const int mat = gid >> 14, r4 = gid & 16383;
  const float* srcs[3] = {w0, w1, w2};
  float4 v = *(const float4*)(srcs[mat] + (size_t)r4 * 4);
  s4v o; o[0] = f2bf(v.x); o[1] = f2bf(v.y); o[2] = f2bf(v.z); o[3] = f2bf(v.w);
  *(s4v*)(wb + (size_t)mat * 65536 + r4 * 4) = o;
}

// ---------------- staged GEMM (bf16 out), 2-phase dbuf, folded per-batch W ----------------
// v = gelu(sum_c W'[b][o][c]*xt[m][c] + b'[b][o]). 128x256 tile, 4 waves x (64x128).
template<int ACT>
__global__ __launch_bounds__(256, 2)
void k_gemm0(const short* __restrict__ A, const short* __restrict__ Wf,
             const float* __restrict__ bfold, short* __restrict__ outp){
  __shared__ short sA[2][128 * 32];
  __shared__ short sB[2][256 * 32];
  const int t = threadIdx.x, l = t & 63, w = t >> 6;
  const int wr = w >> 1, wc = w & 1;
  const int lm = l & 15, lk = l >> 4;
  const size_t m0 = (size_t)blockIdx.x * 128;
  const int b = (int)(m0 >> 14);
  const short* W = Wf + (size_t)b * 65536;
  const float* bias = bfold + b * 256;
  const int swz = ((lk ^ ((lm >> 1) & 3)) << 4);
  f32x4 acc[4][8] = {};

  auto stage = [&](int ks, int buf){
    const int k0 = ks * 32;
#pragma unroll
    for (int p = 0; p < 2; ++p){
      const int q = p * 256 + t, r = q >> 2, kc = q & 3;
      gload16(A + (m0 + r) * 256 + k0 + ((kc ^ ((r >> 1) & 3)) << 3),
              (char*)(&sA[buf][0]) + (p * 256 + w * 64) * 16);
    }
#pragma unroll
    for (int p = 0; p < 4; ++p){
      const int q = p * 256 + t, r = q >> 2, kc = q & 3;
      gload16(W + (size_t)r * 256 + k0 + ((kc ^ ((r >> 1) & 3)) << 3),
              (char*)(&sB[buf][0]) + (p * 256 + w * 64) * 16);
    }
  };

  stage(0, 0);
  __syncthreads();
  int cur = 0;
  for (int ks = 0; ks < 8; ++ks){
    if (ks < 7) stage(ks + 1, cur ^ 1);
    bf8 af[4], bfv[8];
#pragma unroll
    for (int mi = 0; mi < 4; ++mi)
      af[mi] = *(const bf8*)((const char*)(&sA[cur][0]) + (wr * 64 + mi * 16 + lm) * 64 + swz);
#pragma unroll
    for (int ni = 0; ni < 8; ++ni)
      bfv[ni] = *(const bf8*)((const char*)(&sB[cur][0]) + (wc * 128 + ni * 16 + lm) * 64 + swz);
#pragma unroll
    for (int mi = 0; mi < 4; ++mi)
#pragma unroll
      for (int ni = 0; ni < 8; ++ni)
        acc[mi][ni] = __builtin_amdgcn_mfma_f32_16x16x32_bf16(bfv[ni], af[mi], acc[mi][ni], 0, 0, 0);
    __syncthreads();
    cur ^= 1;
  }

#pragma unroll
  for (int ni = 0; ni < 8; ++ni){
    const int ob = wc * 128 + ni * 16 + lk * 4;
    const float4 b4 = *(const float4*)(bias + ob);
#pragma unroll
    for (int mi = 0; mi < 4; ++mi){
      const int px = wr * 64 + mi * 16 + lm;
      s4v o4;
#pragma unroll
      for (int j = 0; j < 4; ++j){
        float v = acc[mi][ni][j] + ((const float*)&b4)[j];
        if (ACT == 1) v = act_gelu(v);
        else if (ACT == 2) v = act_softplus(v);
        o4[j] = f2bf(v);
      }
      *(s4v*)(outp + (m0 + px) * 256 + ob) = o4;
    }
  }
}

// -------- fused chain: out = softplus(gelu(xt*W1'+b1')*W2+b2), 128-px tile, 512 thr --------
// 3-deep counted-vmcnt pipeline (T3/T4): stage(ks+2) each iter, s_waitcnt vmcnt(3/2) (never
// full drain in-loop) + raw s_barrier. 8 waves: p=w>>2 px-half, hh=w&3 ch-quarter.
__global__ __launch_bounds__(512, 1)
void k_chain(const short* __restrict__ A, const short* __restrict__ W1f, const float* __restrict__ b1f,
             const short* __restrict__ W2, const float* __restrict__ b2, short* __restrict__ out){
  __shared__ short sA[3][128 * 32];   // 8KB x3
  __shared__ short sB[3][256 * 32];   // 16KB x3
  __shared__ short h1[128 * 256];     // 64KB, 512B rows, 16B-slot XOR layout
  const int t = threadIdx.x, l = t & 63, w = t >> 6;
  const int p = w >> 2, hh = w & 3;
  const int lm = l & 15, lk = l >> 4;
  const size_t m0 = (size_t)blockIdx.x * 128;
  const int b = (int)(m0 >> 14);
  const short* W1 = W1f + (size_t)b * 65536;
  const float* b1 = b1f + b * 256;
  const int swz = ((lk ^ ((lm >> 1) & 3)) << 4);
  f32x4 acc[4][4] = {};

  auto stageA = [&](int ks, int buf){       // 1 vmem instr
    const int r = t >> 2, kc = t & 3;
    gload16(A + (m0 + r) * 256 + ks * 32 + ((kc ^ ((r >> 1) & 3)) << 3),
            (char*)(&sA[buf][0]) + t * 16);
  };
  auto stageW = [&](const short* Wm, int ks, int buf){   // 2 vmem instr
#pragma unroll
    for (int pp = 0; pp < 2; ++pp){
      const int q = pp * 512 + t, r = q >> 2, kc = q & 3;
      gload16(Wm + (size_t)r * 256 + ks * 32 + ((kc ^ ((r >> 1) & 3)) << 3),
              (char*)(&sB[buf][0]) + q * 16);
    }
  };

  // ---- pass 1: h1 = gelu(xt*W1' + b1') ----
  stageA(0, 0); stageW(W1, 0, 0);
  stageA(1, 1); stageW(W1, 1, 1);
  VM_WAIT(3);                 // slice0 (3 loads) retired; slice1 in flight
  SBAR();
  for (int ks = 0; ks < 8; ++ks){
    const int cur = ks % 3;
    if (ks < 6){ stageA(ks + 2, (ks + 2) % 3); stageW(W1, ks + 2, (ks + 2) % 3); }
    bf8 af[4], bfv[4];
#pragma unroll
    for (int mi = 0; mi < 4; ++mi)
      af[mi] = *(const bf8*)((const char*)(&sA[cur][0]) + (p * 64 + mi * 16 + lm) * 64 + swz);
#pragma unroll
    for (int ni = 0; ni < 4; ++ni)
      bfv[ni] = *(const bf8*)((const char*)(&sB[cur][0]) + (hh * 64 + ni * 16 + lm) * 64 + swz);
#pragma unroll
    for (int mi = 0; mi < 4; ++mi)
#pragma unroll
      for (int ni = 0; ni < 4; ++ni)
        acc[mi][ni] = __builtin_amdgcn_mfma_f32_16x16x32_bf16(bfv[ni], af[mi], acc[mi][ni], 0, 0, 0);
    if (ks < 6) { VM_WAIT(3); } else { VM_WAIT(0); }
    SBAR();
  }
  // h1 epilogue (swapped layout -> packed 8B LDS stores)
#pragma unroll
  for (int ni = 0; ni < 4; ++ni){
    const int ob = hh * 64 + ni * 16 + lk * 4;
    const float4 b4 = *(const float4*)(b1 + ob);
#pragma unroll
    for (int mi = 0; mi < 4; ++mi){
      const int px = p * 64 + mi * 16 + lm;
      s4v o4;
#pragma unroll
      for (int j = 0; j < 4; ++j)
        o4[j] = f2bf(act_gelu(acc[mi][ni][j] + ((const float*)&b4)[j]));
      const int slot = (ob >> 3) ^ (px & 7);
      *(s4v*)((char*)h1 + px * 512 + (slot << 4) + (ob & 4) * 2) = o4;
      acc[mi][ni] = (f32x4){0.f, 0.f, 0.f, 0.f};
    }
  }
  // W2 prologue under the epilogue tail
  stageW(W2, 0, 0); stageW(W2, 1, 1);
  LGKM0();                    // h1 writes visible
  VM_WAIT(2);                 // W2 slice0 retired; slice1 in flight
  SBAR();

  // ---- pass 2: out = softplus(h1*W2 + b2), W2 3-deep, h1 resident ----
  for (int ks = 0; ks < 8; ++ks){
    const int cur = ks % 3;
    if (ks < 6) stageW(W2, ks + 2, (ks + 2) % 3);
    bf8 af[4], bfv[4];
#pragma unroll
    for (int mi = 0; mi < 4; ++mi){
      const int row = p * 64 + mi * 16 + lm;
      const int slot = (ks * 4 + lk) ^ (row & 7);
      af[mi] = *(const bf8*)((const char*)h1 + row * 512 + (slot << 4));
    }
#pragma unroll
    for (int ni = 0; ni < 4; ++ni)
      bfv[ni] = *(const bf8*)((const char*)(&sB[cur][0]) + (hh * 64 + ni * 16 + lm) * 64 + swz);
#pragma unroll
    for (int mi = 0; mi < 4; ++mi)
#pragma unroll
      for (int ni = 0; ni < 4; ++ni)
        acc[mi][ni] = __builtin_amdgcn_mfma_f32_16x16x32_bf16(bfv[ni], af[mi], acc[mi][ni], 0, 0, 0);
    if (ks < 6) { VM_WAIT(2); } else { VM_WAIT(0); }
    SBAR();
  }
#pragma unroll
  for (int ni = 0; ni < 4; ++ni){
    const int ob = hh * 64 + ni * 16 + lk * 4;
    const float4 b4 = *(const float4*)(b2 + ob);
#pragma unroll
    for (int mi = 0; mi < 4; ++mi){
      const int px = p * 64 + mi * 16 + lm;
      s4v o4;
#pragma unroll
      for (int j = 0; j < 4; ++j)
        o4[j] = f2bf(act_softplus(acc[mi][ni][j] + ((const float*)&b4)[j]));
      *(s4v*)(out + (m0 + px) * 256 + ob) = o4;
    }
  }
}

// ---------- kv partials: kv[c][d] = sum_n K[c][n]*V[d][n], n split 4-way; + ksum ----------
__global__ __launch_bounds__(256) void k_kv(const short* __restrict__ kg, const short* __restrict__ vg,
                                            float* __restrict__ kvpart, float* __restrict__ kspart){
  const int s = blockIdx.x, h = blockIdx.y, b = blockIdx.z;
  __shared__ short sk[64 * 72], sv[64 * 72];
  __shared__ float pl[256][8];
  const int t = threadIdx.x, l = t & 63, w = t >> 6;
  const int lm = l & 15, lk = l >> 4;
  float ksp[8];
#pragma unroll
  for (int j = 0; j < 8; ++j) ksp[j] = 0.f;
  f32x4 acc[4] = {};
  const size_t rowbase = ((size_t)b * 16384 + s * 4096) * 256 + h * 64;

  for (int tt = 0; tt < 64; ++tt){
    __syncthreads();
#pragma unroll
    for (int p = 0; p < 2; ++p){
      const int q = p * 256 + t;
      const int nl = q >> 3, c8 = (q & 7) * 8;
      bf8 kvv = *(const bf8*)(kg + rowbase + (size_t)(tt * 64 + nl) * 256 + c8);
      bf8 vvv = *(const bf8*)(vg + rowbase + (size_t)(tt * 64 + nl) * 256 + c8);
#pragma unroll
      for (int j = 0; j < 8; ++j){
        sk[(c8 + j) * 72 + nl] = kvv[j];
        sv[(c8 + j) * 72 + nl] = vvv[j];
        ksp[j] += bf2f(kvv[j]);
      }
    }
    __syncthreads();
#pragma unroll
    for (int ks = 0; ks < 2; ++ks){
      bf8 ak = *(const bf8*)((const char*)sk + (w * 16 + lm) * 144 + ks * 64 + lk * 16);
#pragma unroll
      for (int ni = 0; ni < 4; ++ni){
        bf8 bv = *(const bf8*)((const char*)sv + (ni * 16 + lm) * 144 + ks * 64 + lk * 16);
        acc[ni] = __builtin_amdgcn_mfma_f32_16x16x32_bf16(ak, bv, acc[ni], 0, 0, 0);
      }
    }
  }
#pragma unroll
  for (int j = 0; j < 8; ++j) pl[t][j] = ksp[j];
  __syncthreads();
  const size_t slot = (size_t)(b * 4 + h) * 4 + s;
  if (t < 64){
    float sum = 0.f;
    const int g8 = t >> 3, j = t & 7;
    for (int m = 0; m < 32; ++m) sum += pl[m * 8 + g8][j];
    kspart[slot * 64 + t] = sum;
  }
  float* kvp = kvpart + slot * 4096;
#pragma unroll
  for (int ni = 0; ni < 4; ++ni)
#pragma unroll
    for (int j = 0; j < 4; ++j){
      const int c = w * 16 + lk * 4 + j, d = ni * 16 + lm;
      kvp[c * 64 + d] = acc[ni][j];
    }
}

// ---------- reduce partials -> kvT (b,h,d,c) bf16 (scale folded) + ksum fp32 ----------
__global__ __launch_bounds__(256) void k_kvred(const float* __restrict__ kvpart, const float* __restrict__ kspart,
                                               short* __restrict__ kvT, float* __restrict__ ksum_s){
  const int gid = blockIdx.x * 256 + threadIdx.x;
#pragma unroll
  for (int i = 0; i < 8; ++i){
    const int o = gid * 8 + i;
    const int bh = o >> 12, rem = o & 4095, d = rem >> 6, c = rem & 63;
    float sum = 0.f;
#pragma unroll
    for (int s = 0; s < 4; ++s) sum += kvpart[((size_t)bh * 4 + s) * 4096 + c * 64 + d];
    kvT[o] = f2bf(sum * 0.125f);
  }
  if (gid < 2048){
    float sum = 0.f;
#pragma unroll
    for (int s = 0; s < 4; ++s) sum += kspart[((size_t)(gid >> 6) * 4 + s) * 64 + (gid & 63)];
    ksum_s[gid] = sum * 0.125f;
  }
}

// ---------- FUSED: g-GEMM + attention finalize + final conv, 128-px tile, 512 thr ----------
// Phase 1: g = gelu(xt*Wg'+bg') (swapped, 3-deep) -> kept in registers (layout matches PV).
// Phase 2: z-dot + PV (q,kvT direct); y=(pv+v)*z*g -> LDS (slot-XOR); Wo slices 0,1 staged
//          under phase 2. Phase 3: out = y*Wo + bo (unswapped, Wo 3-deep) -> fp32 CHW.
__global__ __launch_bounds__(512, 1)
void k_fuse(const short* __restrict__ xt, const short* __restrict__ qg,
            const short* __restrict__ vg, const short* __restrict__ kvT,
            const float* __restrict__ ksum_s,
            const short* __restrict__ Wgf, const float* __restrict__ bgf,
            const short* __restrict__ Wo, const float* __restrict__ bo,
            float* __restrict__ outp){
  __shared__ short sA[3][128 * 32];   // 8KB x3
  __shared__ short sB[3][256 * 32];   // 16KB x3
  __shared__ short yl[128 * 256];     // 64KB
  __shared__ float sz[512];
  __shared__ float sks[256];
  const int t = threadIdx.x, l = t & 63, w = t >> 6;
  const int p = w >> 2, hh = w & 3;
  const int lm = l & 15, lk = l >> 4;
  const size_t m0 = (size_t)blockIdx.x * 128;
  const int b = (int)(m0 >> 14);
  const short* Wg = Wgf + (size_t)b * 65536;
  const float* bg = bgf + b * 256;
  const int swz = ((lk ^ ((lm >> 1) & 3)) << 4);

  if (t < 256) sks[t] = ksum_s[b * 256 + t];

  auto stageA = [&](int ks, int buf){       // 1 vmem instr
    const int r = t >> 2, kc = t & 3;
    gload16(xt + (m0 + r) * 256 + ks * 32 + ((kc ^ ((r >> 1) & 3)) << 3),
            (char*)(&sA[buf][0]) + t * 16);
  };
  auto stageW = [&](const short* Wm, int ks, int buf){   // 2 vmem instr
#pragma unroll
    for (int pp = 0; pp < 2; ++pp){
      const int q = pp * 512 + t, r = q >> 2, kc = q & 3;
      gload16(Wm + (size_t)r * 256 + ks * 32 + ((kc ^ ((r >> 1) & 3)) << 3),
              (char*)(&sB[buf][0]) + q * 16);
    }
  };

  f32x4 acc[4][4] = {};

  // ---- phase 1: g = gelu(xt*Wg' + bg'), swapped, 3-deep ----
  stageA(0, 0); stageW(Wg, 0, 0);
  stageA(1, 1); stageW(Wg, 1, 1);
  LGKM0();                    // sks visible
  VM_WAIT(3);
  SBAR();
  for (int ks = 0; ks < 8; ++ks){
    const int cur = ks % 3;
    if (ks < 6){ stageA(ks + 2, (ks + 2) % 3); stageW(Wg, ks + 2, (ks + 2) % 3); }
    bf8 af[4], bfv[4];
#pragma unroll
    for (int mi = 0; mi < 4; ++mi)
      af[mi] = *(const bf8*)((const char*)(&sA[cur][0]) + (p * 64 + mi * 16 + lm) * 64 + swz);
#pragma unroll
    for (int ni = 0; ni < 4; ++ni)
      bfv[ni] = *(const bf8*)((const char*)(&sB[cur][0]) + (hh * 64 + ni * 16 + lm) * 64 + swz);
#pragma unroll
    for (int mi = 0; mi < 4; ++mi)
#pragma unroll
      for (int ni = 0; ni < 4; ++ni)
        acc[mi][ni] = __builtin_amdgcn_mfma_f32_16x16x32_bf16(bfv[ni], af[mi], acc[mi][ni], 0, 0, 0);
    if (ks < 6) { VM_WAIT(3); } else { VM_WAIT(0); }
    SBAR();
  }
  s4v g_pk[4][4];                     // g packed bf16, 32 VGPRs
#pragma unroll
  for (int ni = 0; ni < 4; ++ni){
    const int ob = hh * 64 + ni * 16 + lk * 4;
    const float4 b4 = *(const float4*)(bg + ob);
#pragma unroll
    for (int mi = 0; mi < 4; ++mi){
#pragma unroll
      for (int j = 0; j < 4; ++j)
        g_pk[mi][ni][j] = f2bf(act_gelu(acc[mi][ni][j] + ((const float*)&b4)[j]));
      acc[mi][ni] = (f32x4){0.f, 0.f, 0.f, 0.f};
    }
  }
  // Wo slices 0,1: land during phase 2
  stageW(Wo, 0, 0); stageW(Wo, 1, 1);

  // ---- phase 2: z-dot + PV + y epilogue into LDS ----
  {
    const int px = p * 64 + l;
    float dot = 0.f;
#pragma unroll
    for (int cc = 0; cc < 8; ++cc){
      bf8 qv = *(const bf8*)(qg + (m0 + px) * 256 + hh * 64 + cc * 8);
#pragma unroll
      for (int j = 0; j < 8; ++j) dot += bf2f(qv[j]) * sks[hh * 64 + cc * 8 + j];
    }
    sz[hh * 128 + px] = 1.0f / (dot + 16384.0f);
  }
  const short* kvb = kvT + (size_t)b * 16384;
#pragma unroll
  for (int ks = 0; ks < 2; ++ks){
    bf8 aq[4];
#pragma unroll
    for (int mi = 0; mi < 4; ++mi)
      aq[mi] = *(const bf8*)(qg + (m0 + p * 64 + mi * 16 + lm) * 256 + hh * 64 + ks * 32 + lk * 8);
#pragma unroll
    for (int ni = 0; ni < 4; ++ni){
      bf8 bk = *(const bf8*)(kvb + (size_t)(hh * 64 + ni * 16 + lm) * 64 + ks * 32 + lk * 8);
#pragma unroll
      for (int mi = 0; mi < 4; ++mi)
        acc[mi][ni] = __builtin_amdgcn_mfma_f32_16x16x32_bf16(bk, aq[mi], acc[mi][ni], 0, 0, 0);
    }
  }
#pragma unroll
  for (int mi = 0; mi < 4; ++mi){
    const int px = p * 64 + mi * 16 + lm;
    const float zf = sz[hh * 128 + px];       // own wave's write
    const size_t base = (m0 + px) * 256;
#pragma unroll
    for (int ni = 0; ni < 4; ++ni){
      const int ch = hh * 64 + ni * 16 + lk * 4;
      s4v v4 = *(const s4v*)(vg + base + ch);
      s4v o4;
#pragma unroll
      for (int j = 0; j < 4; ++j)
        o4[j] = f2bf((acc[mi][ni][j] + bf2f(v4[j])) * zf * bf2f(g_pk[mi][ni][j]));
      const int slot = (ch >> 3) ^ (px & 7);
      *(s4v*)((char*)yl + px * 512 + (slot << 4) + (ch & 4) * 2) = o4;
      acc[mi][ni] = (f32x4){0.f, 0.f, 0.f, 0.f};
    }
  }
  LGKM0();                    // yl writes visible
  VM_WAIT(2);                 // Wo slice0 retired; slice1 in flight
  SBAR();

  // ---- phase 3: out = y*Wo + bo (UNSWAPPED), Wo 3-deep, fp32 CHW stores ----
  for (int ks = 0; ks < 8; ++ks){
    const int cur = ks % 3;
    if (ks < 6) stageW(Wo, ks + 2, (ks + 2) % 3);
    bf8 af[4], bfv[4];
#pragma unroll
    for (int mi = 0; mi < 4; ++mi){
      const int row = p * 64 + mi * 16 + lm;
      const int slot = (ks * 4 + lk) ^ (row & 7);
      af[mi] = *(const bf8*)((const char*)yl + row * 512 + (slot << 4));
    }
#pragma unroll
    for (int ni = 0; ni < 4; ++ni)
      bfv[ni] = *(const bf8*)((const char*)(&sB[cur][0]) + (hh * 64 + ni * 16 + lm) * 64 + swz);
#pragma unroll
    for (int mi = 0; mi < 4; ++mi)
#pragma unroll
      for (int ni = 0; ni < 4; ++ni)
        acc[mi][ni] = __builtin_amdgcn_mfma_f32_16x16x32_bf16(af[mi], bfv[ni], acc[mi][ni], 0, 0, 0);
    if (ks < 6) { VM_WAIT(2); } else { VM_WAIT(0); }
    SBAR();
  }
  const int nb = (int)(m0 & 16383);
#pragma unroll
  for (int mi = 0; mi < 4; ++mi){
    const int np = nb + p * 64 + mi * 16 + lk * 4;
#pragma unroll
    for (int ni = 0; ni < 4; ++ni){
      const int o = hh * 64 + ni * 16 + lm;
      const float bi = bo[o];
      float4 v;
      v.x = acc[mi][ni][0] + bi; v.y = acc[mi][ni][1] + bi;
      v.z = acc[mi][ni][2] + bi; v.w = acc[mi][ni][3] + bi;
      *(float4*)(outp + (((size_t)(b * 256 + o)) * 16384 + np)) = v;
    }
  }
}

extern "C" void kernel_launch(void* const* d_in, const int* in_sizes, int n_in,
                              void* d_out, int out_size, void* d_ws, size_t ws_size,
                              hipStream_t stream){
  (void)in_sizes; (void)n_in; (void)out_size; (void)ws_size;
  const float* x   = (const float*)d_in[0];
  const float* wq1 = (const float*)d_in[1];
  const float* bq1 = (const float*)d_in[2];
  const float* wq2 = (const float*)d_in[3];
  const float* bq2 = (const float*)d_in[4];
  const float* wk1 = (const float*)d_in[5];
  const float* bk1 = (const float*)d_in[6];
  const float* wk2 = (const float*)d_in[7];
  const float* bk2 = (const float*)d_in[8];
  const float* wv  = (const float*)d_in[9];
  const float* bv  = (const float*)d_in[10];
  const float* wg  = (const float*)d_in[11];
  const float* bg  = (const float*)d_in[12];
  const float* wo  = (const float*)d_in[13];
  const float* bo  = (const float*)d_in[14];

  char* ws = (char*)d_ws;
  float* mu     = (float*)(ws + 0);                // 8KB
  float* rsig   = (float*)(ws + 8192);             // 8KB
  short* wb     = (short*)(ws + 16384);            // 3 x 128KB bf16 (Wq2, Wk2, Wo)
  float* bfold  = (float*)(ws + 409600);           // 4 mats x 8 b x 256 fp32 = 32KB
  short* wf     = (short*)(ws + 442368);           // 4 mats x 8 b x 64K bf16 = 4MB
  float* ps1    = (float*)(ws + 442368);           // 2MB (dead before k_wfold writes wf)
  float* ps2    = (float*)(ws + 2539520);          // 2MB
  float* kvpart = (float*)(ws + 4636672);          // 2MB (4 splits)
  float* kspart = (float*)(ws + 6733824);          // 32KB
  short* kvT    = (short*)(ws + 6766592);          // 256KB
  float* ksum_s = (float*)(ws + 7028736);          // 8KB
  short* B0 = (short*)(ws + 8388608);              // xt
  short* B1 = B0 + 33554432;                       // v
  short* B2 = B1 + 33554432;                       // q
  short* B3 = B2 + 33554432;                       // k

  k_wconv<<<192, 256, 0, stream>>>(wq2, wk2, wo, wb);
  k_statst<<<dim3(256, 4, 8), 256, 0, stream>>>(x, B0, ps1, ps2);
  k_red<<<2048, 256, 0, stream>>>(ps1, ps2, mu, rsig);
  k_wfold<<<32, 256, 0, stream>>>(wq1, bq1, wk1, bk1, wv, bv, wg, bg, mu, rsig, wf, bfold);
  k_chain<<<1024, 512, 0, stream>>>(B0, wf + 0 * 524288, bfold + 0 * 2048,
                                    wb + 0 * 65536, bq2, B2);           // q
  k_chain<<<1024, 512, 0, stream>>>(B0, wf + 1 * 524288, bfold + 1 * 2048,
                                    wb + 1 * 65536, bk2, B3);           // k
  k_gemm0<1><<<1024, 256, 0, stream>>>(B0, wf + 2 * 524288, bfold + 2 * 2048, B1); // v
  k_kv<<<dim3(4, 4, 8), 256, 0, stream>>>(B3, B1, kvpart, kspart);
  k_kvred<<<64, 256, 0, stream>>>(kvpart, kspart, kvT, ksum_s);
  k_fuse<<<1024, 512, 0, stream>>>(B0, B2, B1, kvT, ksum_s,
                                   wf + 3 * 524288, bfold + 3 * 2048,
                                   wb + 2 * 65536, bo, (float*)d_out);  // g+attn+final
}

// Round 9
// 525.732 us; speedup vs baseline: 1.0237x; 1.0237x over previous
//
#include <hip/hip_runtime.h>
#include <stdint.h>

typedef short bf8 __attribute__((ext_vector_type(8)));   // 8 bf16 in 4 VGPR
typedef short s4v __attribute__((ext_vector_type(4)));   // 4 bf16 = 8B
typedef float f32x4 __attribute__((ext_vector_type(4)));

__device__ __forceinline__ short f2bf(float f){
  union { float f; unsigned u; } c; c.f = f;
  unsigned r = (c.u + 0x7fffu + ((c.u >> 16) & 1u)) >> 16;
  return (short)r;
}
__device__ __forceinline__ float bf2f(short s){
  union { unsigned u; float f; } c; c.u = ((unsigned)(unsigned short)s) << 16;
  return c.f;
}
__device__ __forceinline__ void gload16(const void* g, void* l){
  __builtin_amdgcn_global_load_lds((const __attribute__((address_space(1))) uint32_t*)g,
                                   (__attribute__((address_space(3))) uint32_t*)l, 16, 0, 0);
}
// Fast erf: Abramowitz-Stegun 7.1.26, |err| <= 1.5e-7, branchless ~14 VALU inst.
__device__ __forceinline__ float fast_erf(float x){
  const float s = fabsf(x);
  const float t = __builtin_amdgcn_rcpf(fmaf(0.3275911f, s, 1.0f));
  float p = fmaf(1.061405429f, t, -1.453152027f);
  p = fmaf(p, t, 1.421413741f);
  p = fmaf(p, t, -0.284496736f);
  p = fmaf(p, t, 0.254829592f);
  p = p * t;
  const float e = __expf(-s * s);
  return copysignf(fmaf(-p, e, 1.0f), x);
}
__device__ __forceinline__ float act_gelu(float x){
  return 0.5f * x * (1.0f + fast_erf(x * 0.70710678118654752f));
}
__device__ __forceinline__ float act_softplus(float x){
  const float e = __expf(-fabsf(x));
  return fmaxf(x, 0.0f) + __logf(1.0f + e);
}

// ---- stats + transpose: read x (B,C,N) f32 once; write xt (B,N,C) bf16 (UNnormalized)
//      and per-(b,c) partial sums over each 64-px tile. Norm folded into weights. ----
__global__ __launch_bounds__(256) void k_statst(const float* __restrict__ x, short* __restrict__ xt,
                                                float* __restrict__ ps1, float* __restrict__ ps2){
  const int n0 = blockIdx.x * 64, c0 = blockIdx.y * 64, b = blockIdx.z;
  __shared__ short lt[64][68];
  const int t = threadIdx.x, nj = (t & 15) * 4, cb = t >> 4;
  float s1[4] = {0.f,0.f,0.f,0.f}, s2[4] = {0.f,0.f,0.f,0.f};
#pragma unroll
  for (int it = 0; it < 4; ++it){
    const int ci = cb + it * 16;
    const int row = b * 256 + c0 + ci;
    float4 v = *(const float4*)(x + (size_t)row * 16384 + n0 + nj);
    s4v o;
    o[0] = f2bf(v.x); o[1] = f2bf(v.y); o[2] = f2bf(v.z); o[3] = f2bf(v.w);
    *(s4v*)(&lt[ci][nj]) = o;
    s1[it] += v.x + v.y + v.z + v.w;
    s2[it] += v.x*v.x + v.y*v.y + v.z*v.z + v.w*v.w;
  }
  __syncthreads();
#pragma unroll
  for (int p = 0; p < 2; ++p){
    const int q = p * 256 + t;
    const int nl = q >> 3, c8 = (q & 7) * 8;
    bf8 o;
#pragma unroll
    for (int j = 0; j < 8; ++j) o[j] = lt[c8 + j][nl];
    *(bf8*)(xt + ((size_t)(b * 16384 + n0 + nl)) * 256 + c0 + c8) = o;
  }
#pragma unroll
  for (int it = 0; it < 4; ++it){
#pragma unroll
    for (int off = 8; off > 0; off >>= 1){
      s1[it] += __shfl_down(s1[it], off);
      s2[it] += __shfl_down(s2[it], off);
    }
  }
  if ((t & 15) == 0){
#pragma unroll
    for (int it = 0; it < 4; ++it){
      const int c = c0 + cb + it * 16;
      ps1[((size_t)(b * 256 + c)) * 256 + blockIdx.x] = s1[it];
      ps2[((size_t)(b * 256 + c)) * 256 + blockIdx.x] = s2[it];
    }
  }
}

// ---- reduce 256 tile-partials -> mu, rsig per (b,c) ----
__global__ __launch_bounds__(256) void k_red(const float* __restrict__ ps1, const float* __restrict__ ps2,
                                             float* __restrict__ mu, float* __restrict__ rsig){
  const int bc = blockIdx.x;
  const int t = threadIdx.x;
  __shared__ float a1[256], a2[256];
  a1[t] = ps1[(size_t)bc * 256 + t];
  a2[t] = ps2[(size_t)bc * 256 + t];
  __syncthreads();
  for (int s = 128; s > 0; s >>= 1){
    if (t < s){ a1[t] += a1[t+s]; a2[t] += a2[t+s]; }
    __syncthreads();
  }
  if (t == 0){
    float m = a1[0] * (1.0f/16384.0f);
    float v = a2[0] * (1.0f/16384.0f) - m*m;
    mu[bc] = m; rsig[bc] = rsqrtf(v + 1e-5f);
  }
}

// ---- fold instance-norm into first-layer weights, per batch:
//      W'[b][o][c] = bf16(W[o][c]*rsig[b][c]);  b'[b][o] = b[o] - sum_c W[o][c]*mu[b][c]*rsig[b][c]
__global__ __launch_bounds__(256) void k_wfold(
    const float* __restrict__ w0, const float* __restrict__ bb0,
    const float* __restrict__ w1, const float* __restrict__ bb1,
    const float* __restrict__ w2, const float* __restrict__ bb2,
    const float* __restrict__ w3, const float* __restrict__ bb3,
    const float* __restrict__ mu, const float* __restrict__ rsig,
    short* __restrict__ wf, float* __restrict__ bf){
  const int m = blockIdx.x >> 3, b = blockIdx.x & 7;
  const float* Wm = (m==0)?w0:(m==1)?w1:(m==2)?w2:w3;
  const float* Bm = (m==0)?bb0:(m==1)?bb1:(m==2)?bb2:bb3;
  __shared__ float rs[256], ms[256];
  const int t = threadIdx.x;
  rs[t] = rsig[b*256+t];
  ms[t] = mu[b*256+t] * rs[t];
  __syncthreads();
  short* wout = wf + ((size_t)(m*8+b)) * 65536;
  float* bout = bf + (m*8+b) * 256;
  const int lane = t & 63, wv = t >> 6;
  for (int oi = 0; oi < 64; ++oi){
    const int o = oi * 4 + wv;
    const int c = lane * 4;
    float4 w4 = *(const float4*)(Wm + (size_t)o * 256 + c);
    float pa = w4.x*ms[c] + w4.y*ms[c+1] + w4.z*ms[c+2] + w4.w*ms[c+3];
    s4v o4;
    o4[0] = f2bf(w4.x*rs[c]);   o4[1] = f2bf(w4.y*rs[c+1]);
    o4[2] = f2bf(w4.z*rs[c+2]); o4[3] = f2bf(w4.w*rs[c+3]);
    *(s4v*)(wout + (size_t)o * 256 + c) = o4;
#pragma unroll
    for (int off = 32; off > 0; off >>= 1) pa += __shfl_down(pa, off);
    if (lane == 0) bout[o] = Bm[o] - pa;
  }
}

// ------------- fp32->bf16 weight conversion (3 matrices: Wq2, Wk2, Wo) -------------
__global__ __launch_bounds__(256) void k_wconv(const float* w0, const float* w1, const float* w2,
                                               short* __restrict__ wb){
  const int gid = blockIdx.x * 256 + threadIdx.x;  // 0..49151 float4 chunks
  const int mat = gid >> 14, r4 = gid & 16383;
  const float* srcs[3] = {w0, w1, w2};
  float4 v = *(const float4*)(srcs[mat] + (size_t)r4 * 4);
  s4v o; o[0] = f2bf(v.x); o[1] = f2bf(v.y); o[2] = f2bf(v.z); o[3] = f2bf(v.w);
  *(s4v*)(wb + (size_t)mat * 65536 + r4 * 4) = o;
}

// ---------------- staged GEMM (bf16 out), 2-phase dbuf, folded per-batch W ----------------
// v = gelu(sum_c W'[b][o][c]*xt[m][c] + b'[b][o]). 128x256 tile, 4 waves x (64x128).
template<int ACT>
__global__ __launch_bounds__(256, 2)
void k_gemm0(const short* __restrict__ A, const short* __restrict__ Wf,
             const float* __restrict__ bfold, short* __restrict__ outp){
  __shared__ short sA[2][128 * 32];
  __shared__ short sB[2][256 * 32];
  const int t = threadIdx.x, l = t & 63, w = t >> 6;
  const int wr = w >> 1, wc = w & 1;
  const int lm = l & 15, lk = l >> 4;
  const size_t m0 = (size_t)blockIdx.x * 128;
  const int b = (int)(m0 >> 14);
  const short* W = Wf + (size_t)b * 65536;
  const float* bias = bfold + b * 256;
  const int swz = ((lk ^ ((lm >> 1) & 3)) << 4);
  f32x4 acc[4][8] = {};

  auto stage = [&](int ks, int buf){
    const int k0 = ks * 32;
#pragma unroll
    for (int p = 0; p < 2; ++p){
      const int q = p * 256 + t, r = q >> 2, kc = q & 3;
      gload16(A + (m0 + r) * 256 + k0 + ((kc ^ ((r >> 1) & 3)) << 3),
              (char*)(&sA[buf][0]) + (p * 256 + w * 64) * 16);
    }
#pragma unroll
    for (int p = 0; p < 4; ++p){
      const int q = p * 256 + t, r = q >> 2, kc = q & 3;
      gload16(W + (size_t)r * 256 + k0 + ((kc ^ ((r >> 1) & 3)) << 3),
              (char*)(&sB[buf][0]) + (p * 256 + w * 64) * 16);
    }
  };

  stage(0, 0);
  __syncthreads();
  int cur = 0;
  for (int ks = 0; ks < 8; ++ks){
    if (ks < 7) stage(ks + 1, cur ^ 1);
    bf8 af[4], bfv[8];
#pragma unroll
    for (int mi = 0; mi < 4; ++mi)
      af[mi] = *(const bf8*)((const char*)(&sA[cur][0]) + (wr * 64 + mi * 16 + lm) * 64 + swz);
#pragma unroll
    for (int ni = 0; ni < 8; ++ni)
      bfv[ni] = *(const bf8*)((const char*)(&sB[cur][0]) + (wc * 128 + ni * 16 + lm) * 64 + swz);
#pragma unroll
    for (int mi = 0; mi < 4; ++mi)
#pragma unroll
      for (int ni = 0; ni < 8; ++ni)
        acc[mi][ni] = __builtin_amdgcn_mfma_f32_16x16x32_bf16(bfv[ni], af[mi], acc[mi][ni], 0, 0, 0);
    __syncthreads();
    cur ^= 1;
  }

#pragma unroll
  for (int ni = 0; ni < 8; ++ni){
    const int ob = wc * 128 + ni * 16 + lk * 4;
    const float4 b4 = *(const float4*)(bias + ob);
#pragma unroll
    for (int mi = 0; mi < 4; ++mi){
      const int px = wr * 64 + mi * 16 + lm;
      s4v o4;
#pragma unroll
      for (int j = 0; j < 4; ++j){
        float v = acc[mi][ni][j] + ((const float*)&b4)[j];
        if (ACT == 1) v = act_gelu(v);
        else if (ACT == 2) v = act_softplus(v);
        o4[j] = f2bf(v);
      }
      *(s4v*)(outp + (m0 + px) * 256 + ob) = o4;
    }
  }
}

// -------- fused chain: out = softplus(gelu(xt*W1'+b1')*W2+b2), 64-px tile, 256 thr --------
// r7's proven 2-phase dbuf structure; W1 folded per-batch. W2(ks=0) staged under epilogue.
__global__ __launch_bounds__(256, 2)
void k_chain(const short* __restrict__ A, const short* __restrict__ W1f, const float* __restrict__ b1f,
             const short* __restrict__ W2, const float* __restrict__ b2, short* __restrict__ out){
  __shared__ short sA[2][64 * 32];    // 4KB x2
  __shared__ short sB[2][256 * 32];   // 16KB x2
  __shared__ short h1[64 * 256];      // 32KB, 512B rows, 16B-slot XOR layout
  const int t = threadIdx.x, l = t & 63, w = t >> 6;
  const int lm = l & 15, lk = l >> 4;
  const size_t m0 = (size_t)blockIdx.x * 64;
  const int b = (int)(m0 >> 14);
  const short* W1 = W1f + (size_t)b * 65536;
  const float* b1 = b1f + b * 256;
  const int swz = ((lk ^ ((lm >> 1) & 3)) << 4);
  f32x4 acc[4][4] = {};

  auto stageA = [&](int ks, int buf){
    const int r = t >> 2, kc = t & 3;
    gload16(A + (m0 + r) * 256 + ks * 32 + ((kc ^ ((r >> 1) & 3)) << 3),
            (char*)(&sA[buf][0]) + w * 1024);
  };
  auto stageW = [&](const short* Wm, int ks, int buf){
#pragma unroll
    for (int p = 0; p < 4; ++p){
      const int q = p * 256 + t, r = q >> 2, kc = q & 3;
      gload16(Wm + (size_t)r * 256 + ks * 32 + ((kc ^ ((r >> 1) & 3)) << 3),
              (char*)(&sB[buf][0]) + (p * 256 + w * 64) * 16);
    }
  };

  // ---- pass 1: h1 = gelu(xt*W1' + b1') ----
  stageA(0, 0); stageW(W1, 0, 0);
  __syncthreads();
  int cur = 0;
  for (int ks = 0; ks < 8; ++ks){
    if (ks < 7){ stageA(ks + 1, cur ^ 1); stageW(W1, ks + 1, cur ^ 1); }
    bf8 af[4], bfv[4];
#pragma unroll
    for (int mi = 0; mi < 4; ++mi)
      af[mi] = *(const bf8*)((const char*)(&sA[cur][0]) + (mi * 16 + lm) * 64 + swz);
#pragma unroll
    for (int ni = 0; ni < 4; ++ni)
      bfv[ni] = *(const bf8*)((const char*)(&sB[cur][0]) + (w * 64 + ni * 16 + lm) * 64 + swz);
#pragma unroll
    for (int mi = 0; mi < 4; ++mi)
#pragma unroll
      for (int ni = 0; ni < 4; ++ni)
        acc[mi][ni] = __builtin_amdgcn_mfma_f32_16x16x32_bf16(bfv[ni], af[mi], acc[mi][ni], 0, 0, 0);
    __syncthreads();
    cur ^= 1;
  }

  stageW(W2, 0, 0);                 // issue under the epilogue: latency hides below
#pragma unroll
  for (int ni = 0; ni < 4; ++ni){
    const int ob = w * 64 + ni * 16 + lk * 4;        // 4 consecutive h1 channels
    const float4 b4 = *(const float4*)(b1 + ob);
#pragma unroll
    for (int mi = 0; mi < 4; ++mi){
      const int px = mi * 16 + lm;
      s4v o4;
#pragma unroll
      for (int j = 0; j < 4; ++j)
        o4[j] = f2bf(act_gelu(acc[mi][ni][j] + ((const float*)&b4)[j]));
      const int slot = (ob >> 3) ^ (px & 7);
      *(s4v*)((char*)h1 + px * 512 + (slot << 4) + (ob & 4) * 2) = o4;
      acc[mi][ni] = (f32x4){0.f, 0.f, 0.f, 0.f};
    }
  }
  __syncthreads();                  // drains W2 stage + h1 writes

  // ---- pass 2: out = softplus(h1*W2 + b2) ----
  cur = 0;
  for (int ks = 0; ks < 8; ++ks){
    if (ks < 7) stageW(W2, ks + 1, cur ^ 1);
    bf8 af[4], bfv[4];
#pragma unroll
    for (int mi = 0; mi < 4; ++mi){
      const int row = mi * 16 + lm;
      const int slot = (ks * 4 + lk) ^ (row & 7);
      af[mi] = *(const bf8*)((const char*)h1 + row * 512 + (slot << 4));
    }
#pragma unroll
    for (int ni = 0; ni < 4; ++ni)
      bfv[ni] = *(const bf8*)((const char*)(&sB[cur][0]) + (w * 64 + ni * 16 + lm) * 64 + swz);
#pragma unroll
    for (int mi = 0; mi < 4; ++mi)
#pragma unroll
      for (int ni = 0; ni < 4; ++ni)
        acc[mi][ni] = __builtin_amdgcn_mfma_f32_16x16x32_bf16(bfv[ni], af[mi], acc[mi][ni], 0, 0, 0);
    __syncthreads();
    cur ^= 1;
  }
#pragma unroll
  for (int ni = 0; ni < 4; ++ni){
    const int ob = w * 64 + ni * 16 + lk * 4;
    const float4 b4 = *(const float4*)(b2 + ob);
#pragma unroll
    for (int mi = 0; mi < 4; ++mi){
      const int px = mi * 16 + lm;
      s4v o4;
#pragma unroll
      for (int j = 0; j < 4; ++j)
        o4[j] = f2bf(act_softplus(acc[mi][ni][j] + ((const float*)&b4)[j]));
      *(s4v*)(out + (m0 + px) * 256 + ob) = o4;
    }
  }
}

// ---------- kv partials: kv[c][d] = sum_n K[c][n]*V[d][n], n split 4-way; + ksum ----------
__global__ __launch_bounds__(256) void k_kv(const short* __restrict__ kg, const short* __restrict__ vg,
                                            float* __restrict__ kvpart, float* __restrict__ kspart){
  const int s = blockIdx.x, h = blockIdx.y, b = blockIdx.z;
  __shared__ short sk[64 * 72], sv[64 * 72];
  __shared__ float pl[256][8];
  const int t = threadIdx.x, l = t & 63, w = t >> 6;
  const int lm = l & 15, lk = l >> 4;
  float ksp[8];
#pragma unroll
  for (int j = 0; j < 8; ++j) ksp[j] = 0.f;
  f32x4 acc[4] = {};
  const size_t rowbase = ((size_t)b * 16384 + s * 4096) * 256 + h * 64;

  for (int tt = 0; tt < 64; ++tt){
    __syncthreads();
#pragma unroll
    for (int p = 0; p < 2; ++p){
      const int q = p * 256 + t;
      const int nl = q >> 3, c8 = (q & 7) * 8;
      bf8 kvv = *(const bf8*)(kg + rowbase + (size_t)(tt * 64 + nl) * 256 + c8);
      bf8 vvv = *(const bf8*)(vg + rowbase + (size_t)(tt * 64 + nl) * 256 + c8);
#pragma unroll
      for (int j = 0; j < 8; ++j){
        sk[(c8 + j) * 72 + nl] = kvv[j];
        sv[(c8 + j) * 72 + nl] = vvv[j];
        ksp[j] += bf2f(kvv[j]);
      }
    }
    __syncthreads();
#pragma unroll
    for (int ks = 0; ks < 2; ++ks){
      bf8 ak = *(const bf8*)((const char*)sk + (w * 16 + lm) * 144 + ks * 64 + lk * 16);
#pragma unroll
      for (int ni = 0; ni < 4; ++ni){
        bf8 bv = *(const bf8*)((const char*)sv + (ni * 16 + lm) * 144 + ks * 64 + lk * 16);
        acc[ni] = __builtin_amdgcn_mfma_f32_16x16x32_bf16(ak, bv, acc[ni], 0, 0, 0);
      }
    }
  }
#pragma unroll
  for (int j = 0; j < 8; ++j) pl[t][j] = ksp[j];
  __syncthreads();
  const size_t slot = (size_t)(b * 4 + h) * 4 + s;
  if (t < 64){
    float sum = 0.f;
    const int g8 = t >> 3, j = t & 7;
    for (int m = 0; m < 32; ++m) sum += pl[m * 8 + g8][j];
    kspart[slot * 64 + t] = sum;
  }
  float* kvp = kvpart + slot * 4096;
#pragma unroll
  for (int ni = 0; ni < 4; ++ni)
#pragma unroll
    for (int j = 0; j < 4; ++j){
      const int c = w * 16 + lk * 4 + j, d = ni * 16 + lm;
      kvp[c * 64 + d] = acc[ni][j];
    }
}

// ---------- reduce partials -> kvT (b,h,d,c) bf16 (scale folded) + ksum fp32 ----------
__global__ __launch_bounds__(256) void k_kvred(const float* __restrict__ kvpart, const float* __restrict__ kspart,
                                               short* __restrict__ kvT, float* __restrict__ ksum_s){
  const int gid = blockIdx.x * 256 + threadIdx.x;
#pragma unroll
  for (int i = 0; i < 8; ++i){
    const int o = gid * 8 + i;
    const int bh = o >> 12, rem = o & 4095, d = rem >> 6, c = rem & 63;
    float sum = 0.f;
#pragma unroll
    for (int s = 0; s < 4; ++s) sum += kvpart[((size_t)bh * 4 + s) * 4096 + c * 64 + d];
    kvT[o] = f2bf(sum * 0.125f);
  }
  if (gid < 2048){
    float sum = 0.f;
#pragma unroll
    for (int s = 0; s < 4; ++s) sum += kspart[((size_t)(gid >> 6) * 4 + s) * 64 + (gid & 63)];
    ksum_s[gid] = sum * 0.125f;
  }
}

// ---------- FUSED: g-GEMM + attention finalize + final conv, 64-px tile, 256 thr ----------
// r7's proven structure; Wg folded per-batch. Phase 1: g in registers (layout matches PV).
// Phase 2: z-dot + PV + y -> LDS (slot-XOR). Phase 3: y*Wo + bo -> fp32 CHW float4.
__global__ __launch_bounds__(256, 2)
void k_fuse(const short* __restrict__ xt, const short* __restrict__ qg,
            const short* __restrict__ vg, const short* __restrict__ kvT,
            const float* __restrict__ ksum_s,
            const short* __restrict__ Wgf, const float* __restrict__ bgf,
            const short* __restrict__ Wo, const float* __restrict__ bo,
            float* __restrict__ outp){
  __shared__ short sA[2][64 * 32];    // 4KB x2 (xt staging)
  __shared__ short sB[2][256 * 32];   // 16KB x2 (Wg then Wo staging)
  __shared__ short yl[64 * 256];      // 32KB, 512B rows, 16B-slot XOR layout
  __shared__ float sz[256];
  __shared__ float sks[256];
  const int t = threadIdx.x, l = t & 63, w = t >> 6;
  const int lm = l & 15, lk = l >> 4;
  const size_t m0 = (size_t)blockIdx.x * 64;
  const int b = (int)(m0 >> 14);
  const int h = w;                    // wave == head
  const short* Wg = Wgf + (size_t)b * 65536;
  const float* bg = bgf + b * 256;
  const int swz = ((lk ^ ((lm >> 1) & 3)) << 4);

  sks[t] = ksum_s[b * 256 + t];       // thread t = w*64+l -> wave-local range

  auto stageA = [&](int ks, int buf){
    const int r = t >> 2, kc = t & 3;
    gload16(xt + (m0 + r) * 256 + ks * 32 + ((kc ^ ((r >> 1) & 3)) << 3),
            (char*)(&sA[buf][0]) + w * 1024);
  };
  auto stageW = [&](const short* Wm, int ks, int buf){
#pragma unroll
    for (int p = 0; p < 4; ++p){
      const int q = p * 256 + t, r = q >> 2, kc = q & 3;
      gload16(Wm + (size_t)r * 256 + ks * 32 + ((kc ^ ((r >> 1) & 3)) << 3),
              (char*)(&sB[buf][0]) + (p * 256 + w * 64) * 16);
    }
  };

  f32x4 acc[4][4] = {};

  // ---- phase 1: g = gelu(xt*Wg' + bg'), swapped mfma, kept in registers ----
  stageA(0, 0); stageW(Wg, 0, 0);
  __syncthreads();
  int cur = 0;
  for (int ks = 0; ks < 8; ++ks){
    if (ks < 7){ stageA(ks + 1, cur ^ 1); stageW(Wg, ks + 1, cur ^ 1); }
    bf8 af[4], bfv[4];
#pragma unroll
    for (int mi = 0; mi < 4; ++mi)
      af[mi] = *(const bf8*)((const char*)(&sA[cur][0]) + (mi * 16 + lm) * 64 + swz);
#pragma unroll
    for (int ni = 0; ni < 4; ++ni)
      bfv[ni] = *(const bf8*)((const char*)(&sB[cur][0]) + (w * 64 + ni * 16 + lm) * 64 + swz);
#pragma unroll
    for (int mi = 0; mi < 4; ++mi)
#pragma unroll
      for (int ni = 0; ni < 4; ++ni)
        acc[mi][ni] = __builtin_amdgcn_mfma_f32_16x16x32_bf16(bfv[ni], af[mi], acc[mi][ni], 0, 0, 0);
    __syncthreads();
    cur ^= 1;
  }
  s4v g_pk[4][4];                     // g as packed bf16, 32 VGPRs
#pragma unroll
  for (int ni = 0; ni < 4; ++ni){
    const int ob = h * 64 + ni * 16 + lk * 4;
    const float4 b4 = *(const float4*)(bg + ob);
#pragma unroll
    for (int mi = 0; mi < 4; ++mi){
#pragma unroll
      for (int j = 0; j < 4; ++j)
        g_pk[mi][ni][j] = f2bf(act_gelu(acc[mi][ni][j] + ((const float*)&b4)[j]));
      acc[mi][ni] = (f32x4){0.f, 0.f, 0.f, 0.f};
    }
  }

  // ---- z = 1/(q . ksum + n): lane = pixel, wave = head ----
  {
    float dot = 0.f;
#pragma unroll
    for (int cc = 0; cc < 8; ++cc){
      bf8 qv = *(const bf8*)(qg + (m0 + l) * 256 + h * 64 + cc * 8);
#pragma unroll
      for (int j = 0; j < 8; ++j) dot += bf2f(qv[j]) * sks[h * 64 + cc * 8 + j];
    }
    sz[h * 64 + l] = 1.0f / (dot + 16384.0f);
  }

  // ---- phase 2: PV (swapped) + y epilogue into LDS ----
  const short* kvb = kvT + (size_t)b * 16384;
#pragma unroll
  for (int ks = 0; ks < 2; ++ks){
    bf8 aq[4];
#pragma unroll
    for (int mi = 0; mi < 4; ++mi)
      aq[mi] = *(const bf8*)(qg + (m0 + mi * 16 + lm) * 256 + h * 64 + ks * 32 + lk * 8);
#pragma unroll
    for (int ni = 0; ni < 4; ++ni){
      bf8 bk = *(const bf8*)(kvb + (size_t)(h * 64 + ni * 16 + lm) * 64 + ks * 32 + lk * 8);
#pragma unroll
      for (int mi = 0; mi < 4; ++mi)
        acc[mi][ni] = __builtin_amdgcn_mfma_f32_16x16x32_bf16(bk, aq[mi], acc[mi][ni], 0, 0, 0);
    }
  }
#pragma unroll
  for (int mi = 0; mi < 4; ++mi){
    const int px = mi * 16 + lm;
    const float zf = sz[h * 64 + px];        // own wave's writes
    const size_t base = (m0 + px) * 256;
#pragma unroll
    for (int ni = 0; ni < 4; ++ni){
      const int ch = h * 64 + ni * 16 + lk * 4;
      s4v v4 = *(const s4v*)(vg + base + ch);
      s4v o4;
#pragma unroll
      for (int j = 0; j < 4; ++j)
        o4[j] = f2bf((acc[mi][ni][j] + bf2f(v4[j])) * zf * bf2f(g_pk[mi][ni][j]));
      const int slot = (ch >> 3) ^ (px & 7);
      *(s4v*)((char*)yl + px * 512 + (slot << 4) + (ch & 4) * 2) = o4;
      acc[mi][ni] = (f32x4){0.f, 0.f, 0.f, 0.f};
    }
  }
  stageW(Wo, 0, 0);                   // issue under the epilogue tail
  __syncthreads();                    // drains y writes + Wo stage

  // ---- phase 3: out = y*Wo + bo (UNSWAPPED), fp32 CHW float4 stores ----
  cur = 0;
  for (int ks = 0; ks < 8; ++ks){
    if (ks < 7) stageW(Wo, ks + 1, cur ^ 1);
    bf8 af[4], bfv[4];
#pragma unroll
    for (int mi = 0; mi < 4; ++mi){
      const int row = mi * 16 + lm;
      const int slot = (ks * 4 + lk) ^ (row & 7);
      af[mi] = *(const bf8*)((const char*)yl + row * 512 + (slot << 4));
    }
#pragma unroll
    for (int ni = 0; ni < 4; ++ni)
      bfv[ni] = *(const bf8*)((const char*)(&sB[cur][0]) + (w * 64 + ni * 16 + lm) * 64 + swz);
#pragma unroll
    for (int mi = 0; mi < 4; ++mi)
#pragma unroll
      for (int ni = 0; ni < 4; ++ni)
        acc[mi][ni] = __builtin_amdgcn_mfma_f32_16x16x32_bf16(af[mi], bfv[ni], acc[mi][ni], 0, 0, 0);
    __syncthreads();
    cur ^= 1;
  }
  const int nb = (int)(m0 & 16383);
#pragma unroll
  for (int mi = 0; mi < 4; ++mi){
    const int np = nb + mi * 16 + lk * 4;    // 4 consecutive pixels via f32x4 lanes
#pragma unroll
    for (int ni = 0; ni < 4; ++ni){
      const int o = w * 64 + ni * 16 + lm;
      const float bi = bo[o];
      float4 v;
      v.x = acc[mi][ni][0] + bi; v.y = acc[mi][ni][1] + bi;
      v.z = acc[mi][ni][2] + bi; v.w = acc[mi][ni][3] + bi;
      *(float4*)(outp + (((size_t)(b * 256 + o)) * 16384 + np)) = v;
    }
  }
}

extern "C" void kernel_launch(void* const* d_in, const int* in_sizes, int n_in,
                              void* d_out, int out_size, void* d_ws, size_t ws_size,
                              hipStream_t stream){
  (void)in_sizes; (void)n_in; (void)out_size; (void)ws_size;
  const float* x   = (const float*)d_in[0];
  const float* wq1 = (const float*)d_in[1];
  const float* bq1 = (const float*)d_in[2];
  const float* wq2 = (const float*)d_in[3];
  const float* bq2 = (const float*)d_in[4];
  const float* wk1 = (const float*)d_in[5];
  const float* bk1 = (const float*)d_in[6];
  const float* wk2 = (const float*)d_in[7];
  const float* bk2 = (const float*)d_in[8];
  const float* wv  = (const float*)d_in[9];
  const float* bv  = (const float*)d_in[10];
  const float* wg  = (const float*)d_in[11];
  const float* bg  = (const float*)d_in[12];
  const float* wo  = (const float*)d_in[13];
  const float* bo  = (const float*)d_in[14];

  char* ws = (char*)d_ws;
  float* mu     = (float*)(ws + 0);                // 8KB
  float* rsig   = (float*)(ws + 8192);             // 8KB
  short* wb     = (short*)(ws + 16384);            // 3 x 128KB bf16 (Wq2, Wk2, Wo)
  float* bfold  = (float*)(ws + 409600);           // 4 mats x 8 b x 256 fp32 = 32KB
  short* wf     = (short*)(ws + 442368);           // 4 mats x 8 b x 64K bf16 = 4MB
  float* ps1    = (float*)(ws + 442368);           // 2MB (dead before k_wfold writes wf)
  float* ps2    = (float*)(ws + 2539520);          // 2MB
  float* kvpart = (float*)(ws + 4636672);          // 2MB (4 splits)
  float* kspart = (float*)(ws + 6733824);          // 32KB
  short* kvT    = (short*)(ws + 6766592);          // 256KB
  float* ksum_s = (float*)(ws + 7028736);          // 8KB
  short* B0 = (short*)(ws + 8388608);              // xt
  short* B1 = B0 + 33554432;                       // v
  short* B2 = B1 + 33554432;                       // q
  short* B3 = B2 + 33554432;                       // k

  k_wconv<<<192, 256, 0, stream>>>(wq2, wk2, wo, wb);
  k_statst<<<dim3(256, 4, 8), 256, 0, stream>>>(x, B0, ps1, ps2);
  k_red<<<2048, 256, 0, stream>>>(ps1, ps2, mu, rsig);
  k_wfold<<<32, 256, 0, stream>>>(wq1, bq1, wk1, bk1, wv, bv, wg, bg, mu, rsig, wf, bfold);
  k_chain<<<2048, 256, 0, stream>>>(B0, wf + 0 * 524288, bfold + 0 * 2048,
                                    wb + 0 * 65536, bq2, B2);           // q
  k_chain<<<2048, 256, 0, stream>>>(B0, wf + 1 * 524288, bfold + 1 * 2048,
                                    wb + 1 * 65536, bk2, B3);           // k
  k_gemm0<1><<<1024, 256, 0, stream>>>(B0, wf + 2 * 524288, bfold + 2 * 2048, B1); // v
  k_kv<<<dim3(4, 4, 8), 256, 0, stream>>>(B3, B1, kvpart, kspart);
  k_kvred<<<64, 256, 0, stream>>>(kvpart, kspart, kvT, ksum_s);
  k_fuse<<<2048, 256, 0, stream>>>(B0, B2, B1, kvT, ksum_s,
                                   wf + 3 * 524288, bfold + 3 * 2048,
                                   wb + 2 * 65536, bo, (float*)d_out);  // g+attn+final
}

// Round 10
// 496.232 us; speedup vs baseline: 1.0845x; 1.0594x over previous
//
#include <hip/hip_runtime.h>
#include <stdint.h>

typedef short bf8 __attribute__((ext_vector_type(8)));   // 8 bf16 in 4 VGPR
typedef short s4v __attribute__((ext_vector_type(4)));   // 4 bf16 = 8B
typedef float f32x4 __attribute__((ext_vector_type(4)));

__device__ __forceinline__ short f2bf(float f){
  union { float f; unsigned u; } c; c.f = f;
  unsigned r = (c.u + 0x7fffu + ((c.u >> 16) & 1u)) >> 16;
  return (short)r;
}
__device__ __forceinline__ float bf2f(short s){
  union { unsigned u; float f; } c; c.u = ((unsigned)(unsigned short)s) << 16;
  return c.f;
}
__device__ __forceinline__ void gload16(const void* g, void* l){
  __builtin_amdgcn_global_load_lds((const __attribute__((address_space(1))) uint32_t*)g,
                                   (__attribute__((address_space(3))) uint32_t*)l, 16, 0, 0);
}
// Fast erf: Abramowitz-Stegun 7.1.26, |err| <= 1.5e-7, branchless ~14 VALU inst.
__device__ __forceinline__ float fast_erf(float x){
  const float s = fabsf(x);
  const float t = __builtin_amdgcn_rcpf(fmaf(0.3275911f, s, 1.0f));
  float p = fmaf(1.061405429f, t, -1.453152027f);
  p = fmaf(p, t, 1.421413741f);
  p = fmaf(p, t, -0.284496736f);
  p = fmaf(p, t, 0.254829592f);
  p = p * t;
  const float e = __expf(-s * s);
  return copysignf(fmaf(-p, e, 1.0f), x);
}
__device__ __forceinline__ float act_gelu(float x){
  return 0.5f * x * (1.0f + fast_erf(x * 0.70710678118654752f));
}
__device__ __forceinline__ float act_softplus(float x){
  const float e = __expf(-fabsf(x));
  return fmaxf(x, 0.0f) + __logf(1.0f + e);
}

// ---- stats + transpose: read x (B,C,N) f32 once; write xt (B,N,C) bf16 (UNnormalized)
//      and per-(b,c) partial sums over each 64-px tile. Norm folded into weights. ----
__global__ __launch_bounds__(256) void k_statst(const float* __restrict__ x, short* __restrict__ xt,
                                                float* __restrict__ ps1, float* __restrict__ ps2){
  const int n0 = blockIdx.x * 64, c0 = blockIdx.y * 64, b = blockIdx.z;
  __shared__ short lt[64][68];
  const int t = threadIdx.x, nj = (t & 15) * 4, cb = t >> 4;
  float s1[4] = {0.f,0.f,0.f,0.f}, s2[4] = {0.f,0.f,0.f,0.f};
#pragma unroll
  for (int it = 0; it < 4; ++it){
    const int ci = cb + it * 16;
    const int row = b * 256 + c0 + ci;
    float4 v = *(const float4*)(x + (size_t)row * 16384 + n0 + nj);
    s4v o;
    o[0] = f2bf(v.x); o[1] = f2bf(v.y); o[2] = f2bf(v.z); o[3] = f2bf(v.w);
    *(s4v*)(&lt[ci][nj]) = o;
    s1[it] += v.x + v.y + v.z + v.w;
    s2[it] += v.x*v.x + v.y*v.y + v.z*v.z + v.w*v.w;
  }
  __syncthreads();
#pragma unroll
  for (int p = 0; p < 2; ++p){
    const int q = p * 256 + t;
    const int nl = q >> 3, c8 = (q & 7) * 8;
    bf8 o;
#pragma unroll
    for (int j = 0; j < 8; ++j) o[j] = lt[c8 + j][nl];
    *(bf8*)(xt + ((size_t)(b * 16384 + n0 + nl)) * 256 + c0 + c8) = o;
  }
#pragma unroll
  for (int it = 0; it < 4; ++it){
#pragma unroll
    for (int off = 8; off > 0; off >>= 1){
      s1[it] += __shfl_down(s1[it], off);
      s2[it] += __shfl_down(s2[it], off);
    }
  }
  if ((t & 15) == 0){
#pragma unroll
    for (int it = 0; it < 4; ++it){
      const int c = c0 + cb + it * 16;
      ps1[((size_t)(b * 256 + c)) * 256 + blockIdx.x] = s1[it];
      ps2[((size_t)(b * 256 + c)) * 256 + blockIdx.x] = s2[it];
    }
  }
}

// ---- reduce 256 tile-partials -> mu, rsig per (b,c) ----
__global__ __launch_bounds__(256) void k_red(const float* __restrict__ ps1, const float* __restrict__ ps2,
                                             float* __restrict__ mu, float* __restrict__ rsig){
  const int bc = blockIdx.x;
  const int t = threadIdx.x;
  __shared__ float a1[256], a2[256];
  a1[t] = ps1[(size_t)bc * 256 + t];
  a2[t] = ps2[(size_t)bc * 256 + t];
  __syncthreads();
  for (int s = 128; s > 0; s >>= 1){
    if (t < s){ a1[t] += a1[t+s]; a2[t] += a2[t+s]; }
    __syncthreads();
  }
  if (t == 0){
    float m = a1[0] * (1.0f/16384.0f);
    float v = a2[0] * (1.0f/16384.0f) - m*m;
    mu[bc] = m; rsig[bc] = rsqrtf(v + 1e-5f);
  }
}

// ---- fold instance-norm into first-layer weights, per batch:
//      W'[b][o][c] = bf16(W[o][c]*rsig[b][c]);  b'[b][o] = b[o] - sum_c W[o][c]*mu[b][c]*rsig[b][c]
__global__ __launch_bounds__(256) void k_wfold(
    const float* __restrict__ w0, const float* __restrict__ bb0,
    const float* __restrict__ w1, const float* __restrict__ bb1,
    const float* __restrict__ w2, const float* __restrict__ bb2,
    const float* __restrict__ w3, const float* __restrict__ bb3,
    const float* __restrict__ mu, const float* __restrict__ rsig,
    short* __restrict__ wf, float* __restrict__ bf){
  const int m = blockIdx.x >> 3, b = blockIdx.x & 7;
  const float* Wm = (m==0)?w0:(m==1)?w1:(m==2)?w2:w3;
  const float* Bm = (m==0)?bb0:(m==1)?bb1:(m==2)?bb2:bb3;
  __shared__ float rs[256], ms[256];
  const int t = threadIdx.x;
  rs[t] = rsig[b*256+t];
  ms[t] = mu[b*256+t] * rs[t];
  __syncthreads();
  short* wout = wf + ((size_t)(m*8+b)) * 65536;
  float* bout = bf + (m*8+b) * 256;
  const int lane = t & 63, wv = t >> 6;
  for (int oi = 0; oi < 64; ++oi){
    const int o = oi * 4 + wv;
    const int c = lane * 4;
    float4 w4 = *(const float4*)(Wm + (size_t)o * 256 + c);
    float pa = w4.x*ms[c] + w4.y*ms[c+1] + w4.z*ms[c+2] + w4.w*ms[c+3];
    s4v o4;
    o4[0] = f2bf(w4.x*rs[c]);   o4[1] = f2bf(w4.y*rs[c+1]);
    o4[2] = f2bf(w4.z*rs[c+2]); o4[3] = f2bf(w4.w*rs[c+3]);
    *(s4v*)(wout + (size_t)o * 256 + c) = o4;
#pragma unroll
    for (int off = 32; off > 0; off >>= 1) pa += __shfl_down(pa, off);
    if (lane == 0) bout[o] = Bm[o] - pa;
  }
}

// ------------- fp32->bf16 weight conversion (3 matrices: Wq2, Wk2, Wo) -------------
__global__ __launch_bounds__(256) void k_wconv(const float* w0, const float* w1, const float* w2,
                                               short* __restrict__ wb){
  const int gid = blockIdx.x * 256 + threadIdx.x;  // 0..49151 float4 chunks
  const int mat = gid >> 14, r4 = gid & 16383;
  const float* srcs[3] = {w0, w1, w2};
  float4 v = *(const float4*)(srcs[mat] + (size_t)r4 * 4);
  s4v o; o[0] = f2bf(v.x); o[1] = f2bf(v.y); o[2] = f2bf(v.z); o[3] = f2bf(v.w);
  *(s4v*)(wb + (size_t)mat * 65536 + r4 * 4) = o;
}

// ---------------- staged GEMM (bf16 out), 2-phase dbuf, folded per-batch W ----------------
// v = gelu(sum_c W'[b][o][c]*xt[m][c] + b'[b][o]). 128x256 tile, 4 waves x (64x128).
template<int ACT>
__global__ __launch_bounds__(256, 2)
void k_gemm0(const short* __restrict__ A, const short* __restrict__ Wf,
             const float* __restrict__ bfold, short* __restrict__ outp){
  __shared__ short sA[2][128 * 32];
  __shared__ short sB[2][256 * 32];
  const int t = threadIdx.x, l = t & 63, w = t >> 6;
  const int wr = w >> 1, wc = w & 1;
  const int lm = l & 15, lk = l >> 4;
  const size_t m0 = (size_t)blockIdx.x * 128;
  const int b = (int)(m0 >> 14);
  const short* W = Wf + (size_t)b * 65536;
  const float* bias = bfold + b * 256;
  const int swz = ((lk ^ ((lm >> 1) & 3)) << 4);
  f32x4 acc[4][8] = {};

  auto stage = [&](int ks, int buf){
    const int k0 = ks * 32;
#pragma unroll
    for (int p = 0; p < 2; ++p){
      const int q = p * 256 + t, r = q >> 2, kc = q & 3;
      gload16(A + (m0 + r) * 256 + k0 + ((kc ^ ((r >> 1) & 3)) << 3),
              (char*)(&sA[buf][0]) + (p * 256 + w * 64) * 16);
    }
#pragma unroll
    for (int p = 0; p < 4; ++p){
      const int q = p * 256 + t, r = q >> 2, kc = q & 3;
      gload16(W + (size_t)r * 256 + k0 + ((kc ^ ((r >> 1) & 3)) << 3),
              (char*)(&sB[buf][0]) + (p * 256 + w * 64) * 16);
    }
  };

  stage(0, 0);
  __syncthreads();
  int cur = 0;
  for (int ks = 0; ks < 8; ++ks){
    if (ks < 7) stage(ks + 1, cur ^ 1);
    bf8 af[4], bfv[8];
#pragma unroll
    for (int mi = 0; mi < 4; ++mi)
      af[mi] = *(const bf8*)((const char*)(&sA[cur][0]) + (wr * 64 + mi * 16 + lm) * 64 + swz);
#pragma unroll
    for (int ni = 0; ni < 8; ++ni)
      bfv[ni] = *(const bf8*)((const char*)(&sB[cur][0]) + (wc * 128 + ni * 16 + lm) * 64 + swz);
#pragma unroll
    for (int mi = 0; mi < 4; ++mi)
#pragma unroll
      for (int ni = 0; ni < 8; ++ni)
        acc[mi][ni] = __builtin_amdgcn_mfma_f32_16x16x32_bf16(bfv[ni], af[mi], acc[mi][ni], 0, 0, 0);
    __syncthreads();
    cur ^= 1;
  }

#pragma unroll
  for (int ni = 0; ni < 8; ++ni){
    const int ob = wc * 128 + ni * 16 + lk * 4;
    const float4 b4 = *(const float4*)(bias + ob);
#pragma unroll
    for (int mi = 0; mi < 4; ++mi){
      const int px = wr * 64 + mi * 16 + lm;
      s4v o4;
#pragma unroll
      for (int j = 0; j < 4; ++j){
        float v = acc[mi][ni][j] + ((const float*)&b4)[j];
        if (ACT == 1) v = act_gelu(v);
        else if (ACT == 2) v = act_softplus(v);
        o4[j] = f2bf(v);
      }
      *(s4v*)(outp + (m0 + px) * 256 + ob) = o4;
    }
  }
}

// -------- fused chain: out = softplus(gelu(xt*W1'+b1')*W2+b2), 64-px tile, 256 thr --------
// r7's proven 2-phase dbuf structure; W1 folded per-batch. W2(ks=0) staged under epilogue.
__global__ __launch_bounds__(256, 2)
void k_chain(const short* __restrict__ A, const short* __restrict__ W1f, const float* __restrict__ b1f,
             const short* __restrict__ W2, const float* __restrict__ b2, short* __restrict__ out){
  __shared__ short sA[2][64 * 32];    // 4KB x2
  __shared__ short sB[2][256 * 32];   // 16KB x2
  __shared__ short h1[64 * 256];      // 32KB, 512B rows, 16B-slot XOR layout
  const int t = threadIdx.x, l = t & 63, w = t >> 6;
  const int lm = l & 15, lk = l >> 4;
  const size_t m0 = (size_t)blockIdx.x * 64;
  const int b = (int)(m0 >> 14);
  const short* W1 = W1f + (size_t)b * 65536;
  const float* b1 = b1f + b * 256;
  const int swz = ((lk ^ ((lm >> 1) & 3)) << 4);
  f32x4 acc[4][4] = {};

  auto stageA = [&](int ks, int buf){
    const int r = t >> 2, kc = t & 3;
    gload16(A + (m0 + r) * 256 + ks * 32 + ((kc ^ ((r >> 1) & 3)) << 3),
            (char*)(&sA[buf][0]) + w * 1024);
  };
  auto stageW = [&](const short* Wm, int ks, int buf){
#pragma unroll
    for (int p = 0; p < 4; ++p){
      const int q = p * 256 + t, r = q >> 2, kc = q & 3;
      gload16(Wm + (size_t)r * 256 + ks * 32 + ((kc ^ ((r >> 1) & 3)) << 3),
              (char*)(&sB[buf][0]) + (p * 256 + w * 64) * 16);
    }
  };

  // ---- pass 1: h1 = gelu(xt*W1' + b1') ----
  stageA(0, 0); stageW(W1, 0, 0);
  __syncthreads();
  int cur = 0;
  for (int ks = 0; ks < 8; ++ks){
    if (ks < 7){ stageA(ks + 1, cur ^ 1); stageW(W1, ks + 1, cur ^ 1); }
    bf8 af[4], bfv[4];
#pragma unroll
    for (int mi = 0; mi < 4; ++mi)
      af[mi] = *(const bf8*)((const char*)(&sA[cur][0]) + (mi * 16 + lm) * 64 + swz);
#pragma unroll
    for (int ni = 0; ni < 4; ++ni)
      bfv[ni] = *(const bf8*)((const char*)(&sB[cur][0]) + (w * 64 + ni * 16 + lm) * 64 + swz);
#pragma unroll
    for (int mi = 0; mi < 4; ++mi)
#pragma unroll
      for (int ni = 0; ni < 4; ++ni)
        acc[mi][ni] = __builtin_amdgcn_mfma_f32_16x16x32_bf16(bfv[ni], af[mi], acc[mi][ni], 0, 0, 0);
    __syncthreads();
    cur ^= 1;
  }

  stageW(W2, 0, 0);                 // issue under the epilogue: latency hides below
#pragma unroll
  for (int ni = 0; ni < 4; ++ni){
    const int ob = w * 64 + ni * 16 + lk * 4;        // 4 consecutive h1 channels
    const float4 b4 = *(const float4*)(b1 + ob);
#pragma unroll
    for (int mi = 0; mi < 4; ++mi){
      const int px = mi * 16 + lm;
      s4v o4;
#pragma unroll
      for (int j = 0; j < 4; ++j)
        o4[j] = f2bf(act_gelu(acc[mi][ni][j] + ((const float*)&b4)[j]));
      const int slot = (ob >> 3) ^ (px & 7);
      *(s4v*)((char*)h1 + px * 512 + (slot << 4) + (ob & 4) * 2) = o4;
      acc[mi][ni] = (f32x4){0.f, 0.f, 0.f, 0.f};
    }
  }
  __syncthreads();                  // drains W2 stage + h1 writes

  // ---- pass 2: out = softplus(h1*W2 + b2) ----
  cur = 0;
  for (int ks = 0; ks < 8; ++ks){
    if (ks < 7) stageW(W2, ks + 1, cur ^ 1);
    bf8 af[4], bfv[4];
#pragma unroll
    for (int mi = 0; mi < 4; ++mi){
      const int row = mi * 16 + lm;
      const int slot = (ks * 4 + lk) ^ (row & 7);
      af[mi] = *(const bf8*)((const char*)h1 + row * 512 + (slot << 4));
    }
#pragma unroll
    for (int ni = 0; ni < 4; ++ni)
      bfv[ni] = *(const bf8*)((const char*)(&sB[cur][0]) + (w * 64 + ni * 16 + lm) * 64 + swz);
#pragma unroll
    for (int mi = 0; mi < 4; ++mi)
#pragma unroll
      for (int ni = 0; ni < 4; ++ni)
        acc[mi][ni] = __builtin_amdgcn_mfma_f32_16x16x32_bf16(bfv[ni], af[mi], acc[mi][ni], 0, 0, 0);
    __syncthreads();
    cur ^= 1;
  }
#pragma unroll
  for (int ni = 0; ni < 4; ++ni){
    const int ob = w * 64 + ni * 16 + lk * 4;
    const float4 b4 = *(const float4*)(b2 + ob);
#pragma unroll
    for (int mi = 0; mi < 4; ++mi){
      const int px = mi * 16 + lm;
      s4v o4;
#pragma unroll
      for (int j = 0; j < 4; ++j)
        o4[j] = f2bf(act_softplus(acc[mi][ni][j] + ((const float*)&b4)[j]));
      *(s4v*)(out + (m0 + px) * 256 + ob) = o4;
    }
  }
}

// ---------- kv partials: kv[c][d] = sum_n K[c][n]*V[d][n], n split 8-way; + ksum ----------
// 256 blocks (full CU coverage) — r9's 4-split/128-block config halved CU utilization.
__global__ __launch_bounds__(256) void k_kv(const short* __restrict__ kg, const short* __restrict__ vg,
                                            float* __restrict__ kvpart, float* __restrict__ kspart){
  const int s = blockIdx.x, h = blockIdx.y, b = blockIdx.z;
  __shared__ short sk[64 * 72], sv[64 * 72];
  __shared__ float pl[256][8];
  const int t = threadIdx.x, l = t & 63, w = t >> 6;
  const int lm = l & 15, lk = l >> 4;
  float ksp[8];
#pragma unroll
  for (int j = 0; j < 8; ++j) ksp[j] = 0.f;
  f32x4 acc[4] = {};
  const size_t rowbase = ((size_t)b * 16384 + s * 2048) * 256 + h * 64;

  for (int tt = 0; tt < 32; ++tt){
    __syncthreads();
#pragma unroll
    for (int p = 0; p < 2; ++p){
      const int q = p * 256 + t;
      const int nl = q >> 3, c8 = (q & 7) * 8;
      bf8 kvv = *(const bf8*)(kg + rowbase + (size_t)(tt * 64 + nl) * 256 + c8);
      bf8 vvv = *(const bf8*)(vg + rowbase + (size_t)(tt * 64 + nl) * 256 + c8);
#pragma unroll
      for (int j = 0; j < 8; ++j){
        sk[(c8 + j) * 72 + nl] = kvv[j];
        sv[(c8 + j) * 72 + nl] = vvv[j];
        ksp[j] += bf2f(kvv[j]);
      }
    }
    __syncthreads();
#pragma unroll
    for (int ks = 0; ks < 2; ++ks){
      bf8 ak = *(const bf8*)((const char*)sk + (w * 16 + lm) * 144 + ks * 64 + lk * 16);
#pragma unroll
      for (int ni = 0; ni < 4; ++ni){
        bf8 bv = *(const bf8*)((const char*)sv + (ni * 16 + lm) * 144 + ks * 64 + lk * 16);
        acc[ni] = __builtin_amdgcn_mfma_f32_16x16x32_bf16(ak, bv, acc[ni], 0, 0, 0);
      }
    }
  }
#pragma unroll
  for (int j = 0; j < 8; ++j) pl[t][j] = ksp[j];
  __syncthreads();
  const size_t slot = (size_t)(b * 4 + h) * 8 + s;
  if (t < 64){
    float sum = 0.f;
    const int g8 = t >> 3, j = t & 7;
    for (int m = 0; m < 32; ++m) sum += pl[m * 8 + g8][j];
    kspart[slot * 64 + t] = sum;
  }
  float* kvp = kvpart + slot * 4096;
#pragma unroll
  for (int ni = 0; ni < 4; ++ni)
#pragma unroll
    for (int j = 0; j < 4; ++j){
      const int c = w * 16 + lk * 4 + j, d = ni * 16 + lm;
      kvp[c * 64 + d] = acc[ni][j];
    }
}

// ---------- reduce partials -> kvT (b,h,d,c) bf16 (scale folded) + ksum fp32 ----------
__global__ __launch_bounds__(256) void k_kvred(const float* __restrict__ kvpart, const float* __restrict__ kspart,
                                               short* __restrict__ kvT, float* __restrict__ ksum_s){
  const int gid = blockIdx.x * 256 + threadIdx.x;
#pragma unroll
  for (int i = 0; i < 8; ++i){
    const int o = gid * 8 + i;
    const int bh = o >> 12, rem = o & 4095, d = rem >> 6, c = rem & 63;
    float sum = 0.f;
#pragma unroll
    for (int s = 0; s < 8; ++s) sum += kvpart[((size_t)bh * 8 + s) * 4096 + c * 64 + d];
    kvT[o] = f2bf(sum * 0.125f);
  }
  if (gid < 2048){
    float sum = 0.f;
#pragma unroll
    for (int s = 0; s < 8; ++s) sum += kspart[((size_t)(gid >> 6) * 8 + s) * 64 + (gid & 63)];
    ksum_s[gid] = sum * 0.125f;
  }
}

// ---------- FUSED: g-GEMM + attention finalize + final conv, 64-px tile, 256 thr ----------
// r7's proven structure; Wg folded per-batch. Phase 1: g in registers (layout matches PV).
// Phase 2: z-dot + PV + y -> LDS (slot-XOR). Phase 3: y*Wo + bo -> fp32 CHW float4.
__global__ __launch_bounds__(256, 2)
void k_fuse(const short* __restrict__ xt, const short* __restrict__ qg,
            const short* __restrict__ vg, const short* __restrict__ kvT,
            const float* __restrict__ ksum_s,
            const short* __restrict__ Wgf, const float* __restrict__ bgf,
            const short* __restrict__ Wo, const float* __restrict__ bo,
            float* __restrict__ outp){
  __shared__ short sA[2][64 * 32];    // 4KB x2 (xt staging)
  __shared__ short sB[2][256 * 32];   // 16KB x2 (Wg then Wo staging)
  __shared__ short yl[64 * 256];      // 32KB, 512B rows, 16B-slot XOR layout
  __shared__ float sz[256];
  __shared__ float sks[256];
  const int t = threadIdx.x, l = t & 63, w = t >> 6;
  const int lm = l & 15, lk = l >> 4;
  const size_t m0 = (size_t)blockIdx.x * 64;
  const int b = (int)(m0 >> 14);
  const int h = w;                    // wave == head
  const short* Wg = Wgf + (size_t)b * 65536;
  const float* bg = bgf + b * 256;
  const int swz = ((lk ^ ((lm >> 1) & 3)) << 4);

  sks[t] = ksum_s[b * 256 + t];       // thread t = w*64+l -> wave-local range

  auto stageA = [&](int ks, int buf){
    const int r = t >> 2, kc = t & 3;
    gload16(xt + (m0 + r) * 256 + ks * 32 + ((kc ^ ((r >> 1) & 3)) << 3),
            (char*)(&sA[buf][0]) + w * 1024);
  };
  auto stageW = [&](const short* Wm, int ks, int buf){
#pragma unroll
    for (int p = 0; p < 4; ++p){
      const int q = p * 256 + t, r = q >> 2, kc = q & 3;
      gload16(Wm + (size_t)r * 256 + ks * 32 + ((kc ^ ((r >> 1) & 3)) << 3),
              (char*)(&sB[buf][0]) + (p * 256 + w * 64) * 16);
    }
  };

  f32x4 acc[4][4] = {};

  // ---- phase 1: g = gelu(xt*Wg' + bg'), swapped mfma, kept in registers ----
  stageA(0, 0); stageW(Wg, 0, 0);
  __syncthreads();
  int cur = 0;
  for (int ks = 0; ks < 8; ++ks){
    if (ks < 7){ stageA(ks + 1, cur ^ 1); stageW(Wg, ks + 1, cur ^ 1); }
    bf8 af[4], bfv[4];
#pragma unroll
    for (int mi = 0; mi < 4; ++mi)
      af[mi] = *(const bf8*)((const char*)(&sA[cur][0]) + (mi * 16 + lm) * 64 + swz);
#pragma unroll
    for (int ni = 0; ni < 4; ++ni)
      bfv[ni] = *(const bf8*)((const char*)(&sB[cur][0]) + (w * 64 + ni * 16 + lm) * 64 + swz);
#pragma unroll
    for (int mi = 0; mi < 4; ++mi)
#pragma unroll
      for (int ni = 0; ni < 4; ++ni)
        acc[mi][ni] = __builtin_amdgcn_mfma_f32_16x16x32_bf16(bfv[ni], af[mi], acc[mi][ni], 0, 0, 0);
    __syncthreads();
    cur ^= 1;
  }
  s4v g_pk[4][4];                     // g as packed bf16, 32 VGPRs
#pragma unroll
  for (int ni = 0; ni < 4; ++ni){
    const int ob = h * 64 + ni * 16 + lk * 4;
    const float4 b4 = *(const float4*)(bg + ob);
#pragma unroll
    for (int mi = 0; mi < 4; ++mi){
#pragma unroll
      for (int j = 0; j < 4; ++j)
        g_pk[mi][ni][j] = f2bf(act_gelu(acc[mi][ni][j] + ((const float*)&b4)[j]));
      acc[mi][ni] = (f32x4){0.f, 0.f, 0.f, 0.f};
    }
  }

  // ---- z = 1/(q . ksum + n): lane = pixel, wave = head ----
  {
    float dot = 0.f;
#pragma unroll
    for (int cc = 0; cc < 8; ++cc){
      bf8 qv = *(const bf8*)(qg + (m0 + l) * 256 + h * 64 + cc * 8);
#pragma unroll
      for (int j = 0; j < 8; ++j) dot += bf2f(qv[j]) * sks[h * 64 + cc * 8 + j];
    }
    sz[h * 64 + l] = 1.0f / (dot + 16384.0f);
  }

  // ---- phase 2: PV (swapped) + y epilogue into LDS ----
  const short* kvb = kvT + (size_t)b * 16384;
#pragma unroll
  for (int ks = 0; ks < 2; ++ks){
    bf8 aq[4];
#pragma unroll
    for (int mi = 0; mi < 4; ++mi)
      aq[mi] = *(const bf8*)(qg + (m0 + mi * 16 + lm) * 256 + h * 64 + ks * 32 + lk * 8);
#pragma unroll
    for (int ni = 0; ni < 4; ++ni){
      bf8 bk = *(const bf8*)(kvb + (size_t)(h * 64 + ni * 16 + lm) * 64 + ks * 32 + lk * 8);
#pragma unroll
      for (int mi = 0; mi < 4; ++mi)
        acc[mi][ni] = __builtin_amdgcn_mfma_f32_16x16x32_bf16(bk, aq[mi], acc[mi][ni], 0, 0, 0);
    }
  }
#pragma unroll
  for (int mi = 0; mi < 4; ++mi){
    const int px = mi * 16 + lm;
    const float zf = sz[h * 64 + px];        // own wave's writes
    const size_t base = (m0 + px) * 256;
#pragma unroll
    for (int ni = 0; ni < 4; ++ni){
      const int ch = h * 64 + ni * 16 + lk * 4;
      s4v v4 = *(const s4v*)(vg + base + ch);
      s4v o4;
#pragma unroll
      for (int j = 0; j < 4; ++j)
        o4[j] = f2bf((acc[mi][ni][j] + bf2f(v4[j])) * zf * bf2f(g_pk[mi][ni][j]));
      const int slot = (ch >> 3) ^ (px & 7);
      *(s4v*)((char*)yl + px * 512 + (slot << 4) + (ch & 4) * 2) = o4;
      acc[mi][ni] = (f32x4){0.f, 0.f, 0.f, 0.f};
    }
  }
  stageW(Wo, 0, 0);                   // issue under the epilogue tail
  __syncthreads();                    // drains y writes + Wo stage

  // ---- phase 3: out = y*Wo + bo (UNSWAPPED), fp32 CHW float4 stores ----
  cur = 0;
  for (int ks = 0; ks < 8; ++ks){
    if (ks < 7) stageW(Wo, ks + 1, cur ^ 1);
    bf8 af[4], bfv[4];
#pragma unroll
    for (int mi = 0; mi < 4; ++mi){
      const int row = mi * 16 + lm;
      const int slot = (ks * 4 + lk) ^ (row & 7);
      af[mi] = *(const bf8*)((const char*)yl + row * 512 + (slot << 4));
    }
#pragma unroll
    for (int ni = 0; ni < 4; ++ni)
      bfv[ni] = *(const bf8*)((const char*)(&sB[cur][0]) + (w * 64 + ni * 16 + lm) * 64 + swz);
#pragma unroll
    for (int mi = 0; mi < 4; ++mi)
#pragma unroll
      for (int ni = 0; ni < 4; ++ni)
        acc[mi][ni] = __builtin_amdgcn_mfma_f32_16x16x32_bf16(af[mi], bfv[ni], acc[mi][ni], 0, 0, 0);
    __syncthreads();
    cur ^= 1;
  }
  const int nb = (int)(m0 & 16383);
#pragma unroll
  for (int mi = 0; mi < 4; ++mi){
    const int np = nb + mi * 16 + lk * 4;    // 4 consecutive pixels via f32x4 lanes
#pragma unroll
    for (int ni = 0; ni < 4; ++ni){
      const int o = w * 64 + ni * 16 + lm;
      const float bi = bo[o];
      float4 v;
      v.x = acc[mi][ni][0] + bi; v.y = acc[mi][ni][1] + bi;
      v.z = acc[mi][ni][2] + bi; v.w = acc[mi][ni][3] + bi;
      *(float4*)(outp + (((size_t)(b * 256 + o)) * 16384 + np)) = v;
    }
  }
}

extern "C" void kernel_launch(void* const* d_in, const int* in_sizes, int n_in,
                              void* d_out, int out_size, void* d_ws, size_t ws_size,
                              hipStream_t stream){
  (void)in_sizes; (void)n_in; (void)out_size; (void)ws_size;
  const float* x   = (const float*)d_in[0];
  const float* wq1 = (const float*)d_in[1];
  const float* bq1 = (const float*)d_in[2];
  const float* wq2 = (const float*)d_in[3];
  const float* bq2 = (const float*)d_in[4];
  const float* wk1 = (const float*)d_in[5];
  const float* bk1 = (const float*)d_in[6];
  const float* wk2 = (const float*)d_in[7];
  const float* bk2 = (const float*)d_in[8];
  const float* wv  = (const float*)d_in[9];
  const float* bv  = (const float*)d_in[10];
  const float* wg  = (const float*)d_in[11];
  const float* bg  = (const float*)d_in[12];
  const float* wo  = (const float*)d_in[13];
  const float* bo  = (const float*)d_in[14];

  char* ws = (char*)d_ws;
  float* mu     = (float*)(ws + 0);                // 8KB
  float* rsig   = (float*)(ws + 8192);             // 8KB
  short* wb     = (short*)(ws + 16384);            // 3 x 128KB bf16 (Wq2, Wk2, Wo)
  float* bfold  = (float*)(ws + 409600);           // 4 mats x 8 b x 256 fp32 = 32KB
  short* wf     = (short*)(ws + 442368);           // 4 mats x 8 b x 64K bf16 = 4MB
  float* ps1    = (float*)(ws + 442368);           // 2MB (dead before k_wfold writes wf)
  float* ps2    = (float*)(ws + 2539520);          // 2MB
  float* kvpart = (float*)(ws + 4636672);          // 4MB (8 splits, 256 slots)
  float* kspart = (float*)(ws + 8830976);          // 64KB
  short* kvT    = (short*)(ws + 8896512);          // 256KB
  float* ksum_s = (float*)(ws + 9158656);          // 8KB
  short* B0 = (short*)(ws + 16777216);             // xt (64MB each buffer)
  short* B1 = B0 + 33554432;                       // v
  short* B2 = B1 + 33554432;                       // q
  short* B3 = B2 + 33554432;                       // k

  k_wconv<<<192, 256, 0, stream>>>(wq2, wk2, wo, wb);
  k_statst<<<dim3(256, 4, 8), 256, 0, stream>>>(x, B0, ps1, ps2);
  k_red<<<2048, 256, 0, stream>>>(ps1, ps2, mu, rsig);
  k_wfold<<<32, 256, 0, stream>>>(wq1, bq1, wk1, bk1, wv, bv, wg, bg, mu, rsig, wf, bfold);
  k_chain<<<2048, 256, 0, stream>>>(B0, wf + 0 * 524288, bfold + 0 * 2048,
                                    wb + 0 * 65536, bq2, B2);           // q
  k_chain<<<2048, 256, 0, stream>>>(B0, wf + 1 * 524288, bfold + 1 * 2048,
                                    wb + 1 * 65536, bk2, B3);           // k
  k_gemm0<1><<<1024, 256, 0, stream>>>(B0, wf + 2 * 524288, bfold + 2 * 2048, B1); // v
  k_kv<<<dim3(8, 4, 8), 256, 0, stream>>>(B3, B1, kvpart, kspart);
  k_kvred<<<64, 256, 0, stream>>>(kvpart, kspart, kvT, ksum_s);
  k_fuse<<<2048, 256, 0, stream>>>(B0, B2, B1, kvT, ksum_s,
                                   wf + 3 * 524288, bfold + 3 * 2048,
                                   wb + 2 * 65536, bo, (float*)d_out);  // g+attn+final
}

// Round 11
// 442.097 us; speedup vs baseline: 1.2173x; 1.1225x over previous
//
#include <hip/hip_runtime.h>
#include <stdint.h>

typedef short bf8 __attribute__((ext_vector_type(8)));   // 8 bf16 in 4 VGPR
typedef short s4v __attribute__((ext_vector_type(4)));   // 4 bf16 = 8B
typedef float f32x4 __attribute__((ext_vector_type(4)));

#define VM_WAIT(N) asm volatile("s_waitcnt vmcnt(" #N ")" ::: "memory")
#define LGKM0()    asm volatile("s_waitcnt lgkmcnt(0)" ::: "memory")
#define SBAR()     do { __builtin_amdgcn_sched_barrier(0); __builtin_amdgcn_s_barrier(); \
                        __builtin_amdgcn_sched_barrier(0); } while (0)

__device__ __forceinline__ short f2bf(float f){
  union { float f; unsigned u; } c; c.f = f;
  unsigned r = (c.u + 0x7fffu + ((c.u >> 16) & 1u)) >> 16;
  return (short)r;
}
__device__ __forceinline__ float bf2f(short s){
  union { unsigned u; float f; } c; c.u = ((unsigned)(unsigned short)s) << 16;
  return c.f;
}
__device__ __forceinline__ void gload16(const void* g, void* l){
  __builtin_amdgcn_global_load_lds((const __attribute__((address_space(1))) uint32_t*)g,
                                   (__attribute__((address_space(3))) uint32_t*)l, 16, 0, 0);
}
// Fast erf: Abramowitz-Stegun 7.1.26, |err| <= 1.5e-7, branchless ~14 VALU inst.
__device__ __forceinline__ float fast_erf(float x){
  const float s = fabsf(x);
  const float t = __builtin_amdgcn_rcpf(fmaf(0.3275911f, s, 1.0f));
  float p = fmaf(1.061405429f, t, -1.453152027f);
  p = fmaf(p, t, 1.421413741f);
  p = fmaf(p, t, -0.284496736f);
  p = fmaf(p, t, 0.254829592f);
  p = p * t;
  const float e = __expf(-s * s);
  return copysignf(fmaf(-p, e, 1.0f), x);
}
__device__ __forceinline__ float act_gelu(float x){
  return 0.5f * x * (1.0f + fast_erf(x * 0.70710678118654752f));
}
__device__ __forceinline__ float act_softplus(float x){
  const float e = __expf(-fabsf(x));
  return fmaxf(x, 0.0f) + __logf(1.0f + e);
}

// ---- stats + transpose: read x (B,C,N) f32 once; write xt (B,N,C) bf16 (UNnormalized)
//      and per-(b,c) partial sums over each 64-px tile ----
__global__ __launch_bounds__(256) void k_statst(const float* __restrict__ x, short* __restrict__ xt,
                                                float* __restrict__ ps1, float* __restrict__ ps2){
  const int n0 = blockIdx.x * 64, c0 = blockIdx.y * 64, b = blockIdx.z;
  __shared__ short lt[64][68];
  const int t = threadIdx.x, nj = (t & 15) * 4, cb = t >> 4;
  float s1[4] = {0.f,0.f,0.f,0.f}, s2[4] = {0.f,0.f,0.f,0.f};
#pragma unroll
  for (int it = 0; it < 4; ++it){
    const int ci = cb + it * 16;
    const int row = b * 256 + c0 + ci;
    float4 v = *(const float4*)(x + (size_t)row * 16384 + n0 + nj);
    s4v o;
    o[0] = f2bf(v.x); o[1] = f2bf(v.y); o[2] = f2bf(v.z); o[3] = f2bf(v.w);
    *(s4v*)(&lt[ci][nj]) = o;
    s1[it] += v.x + v.y + v.z + v.w;
    s2[it] += v.x*v.x + v.y*v.y + v.z*v.z + v.w*v.w;
  }
  __syncthreads();
#pragma unroll
  for (int p = 0; p < 2; ++p){
    const int q = p * 256 + t;
    const int nl = q >> 3, c8 = (q & 7) * 8;
    bf8 o;
#pragma unroll
    for (int j = 0; j < 8; ++j) o[j] = lt[c8 + j][nl];
    *(bf8*)(xt + ((size_t)(b * 16384 + n0 + nl)) * 256 + c0 + c8) = o;
  }
#pragma unroll
  for (int it = 0; it < 4; ++it){
#pragma unroll
    for (int off = 8; off > 0; off >>= 1){
      s1[it] += __shfl_down(s1[it], off);
      s2[it] += __shfl_down(s2[it], off);
    }
  }
  if ((t & 15) == 0){
#pragma unroll
    for (int it = 0; it < 4; ++it){
      const int c = c0 + cb + it * 16;
      ps1[((size_t)(b * 256 + c)) * 256 + blockIdx.x] = s1[it];
      ps2[((size_t)(b * 256 + c)) * 256 + blockIdx.x] = s2[it];
    }
  }
}

// ---- reduce 256 tile-partials -> mu, rsig per (b,c) ----
__global__ __launch_bounds__(256) void k_red(const float* __restrict__ ps1, const float* __restrict__ ps2,
                                             float* __restrict__ mu, float* __restrict__ rsig){
  const int bc = blockIdx.x;
  const int t = threadIdx.x;
  __shared__ float a1[256], a2[256];
  a1[t] = ps1[(size_t)bc * 256 + t];
  a2[t] = ps2[(size_t)bc * 256 + t];
  __syncthreads();
  for (int s = 128; s > 0; s >>= 1){
    if (t < s){ a1[t] += a1[t+s]; a2[t] += a2[t+s]; }
    __syncthreads();
  }
  if (t == 0){
    float m = a1[0] * (1.0f/16384.0f);
    float v = a2[0] * (1.0f/16384.0f) - m*m;
    mu[bc] = m; rsig[bc] = rsqrtf(v + 1e-5f);
  }
}

// ---- elementwise normalize xt -> xn, in place (pixel-major bf16) ----
__global__ __launch_bounds__(256) void k_norm(short* xn, const float* __restrict__ mu,
                                              const float* __restrict__ rsig){
  const int g = blockIdx.x * 256 + threadIdx.x;
#pragma unroll
  for (int pass = 0; pass < 8; ++pass){
    const int idx = g + pass * 524288;
    const int bn = idx >> 5, c8 = idx & 31;
    const int b = bn >> 14;
    const float* mp = mu + b * 256 + c8 * 8;
    const float* rp = rsig + b * 256 + c8 * 8;
    float4 m0 = *(const float4*)mp, m1 = *(const float4*)(mp + 4);
    float4 r0 = *(const float4*)rp, r1 = *(const float4*)(rp + 4);
    float mm[8] = {m0.x,m0.y,m0.z,m0.w,m1.x,m1.y,m1.z,m1.w};
    float rr[8] = {r0.x,r0.y,r0.z,r0.w,r1.x,r1.y,r1.z,r1.w};
    bf8 v = *(const bf8*)(xn + (size_t)idx * 8);
    bf8 o;
#pragma unroll
    for (int j = 0; j < 8; ++j) o[j] = f2bf((bf2f(v[j]) - mm[j]) * rr[j]);
    *(bf8*)(xn + (size_t)idx * 8) = o;
  }
}

// ------------- fp32->bf16 weight conversion (7 matrices of 256x256) -------------
__global__ __launch_bounds__(256) void k_wconv(const float* w0, const float* w1, const float* w2,
                                               const float* w3, const float* w4, const float* w5,
                                               const float* w6, short* __restrict__ wb){
  const int gid = blockIdx.x * 256 + threadIdx.x;
  const int mat = gid >> 14, r4 = gid & 16383;
  const float* srcs[7] = {w0, w1, w2, w3, w4, w5, w6};
  float4 v = *(const float4*)(srcs[mat] + (size_t)r4 * 4);
  s4v o; o[0] = f2bf(v.x); o[1] = f2bf(v.y); o[2] = f2bf(v.z); o[3] = f2bf(v.w);
  *(s4v*)(wb + (size_t)mat * 65536 + r4 * 4) = o;
}

// ---------------- staged GEMM (bf16 out), counted-vmcnt 2-buffer pipeline ----------------
// out[m][o] = act(sum_c A[m][c]*W[o][c] + b[o]). 128x256 tile, 4 waves x (64x128).
// T3/T4 at r7 shape: pre-stage slices 0,1; per iter vmcnt(6) (never 0 in-loop) -> bar ->
// ds_read+MFMA -> bar -> stage ks+2 into the freed buffer. Stage gets ~2 iters to fly.
template<int ACT>
__global__ __launch_bounds__(256, 2)
void k_gemm0(const short* __restrict__ A, const short* __restrict__ W,
             const float* __restrict__ bias, short* __restrict__ outp){
  __shared__ short sA[2][128 * 32];
  __shared__ short sB[2][256 * 32];
  const int t = threadIdx.x, l = t & 63, w = t >> 6;
  const int wr = w >> 1, wc = w & 1;
  const int lm = l & 15, lk = l >> 4;
  const size_t m0 = (size_t)blockIdx.x * 128;
  const int swz = ((lk ^ ((lm >> 1) & 3)) << 4);
  f32x4 acc[4][8] = {};

  auto stage = [&](int ks, int buf){      // 6 vmem instr per thread
    const int k0 = ks * 32;
#pragma unroll
    for (int p = 0; p < 2; ++p){
      const int q = p * 256 + t, r = q >> 2, kc = q & 3;
      gload16(A + (m0 + r) * 256 + k0 + ((kc ^ ((r >> 1) & 3)) << 3),
              (char*)(&sA[buf][0]) + (p * 256 + w * 64) * 16);
    }
#pragma unroll
    for (int p = 0; p < 4; ++p){
      const int q = p * 256 + t, r = q >> 2, kc = q & 3;
      gload16(W + (size_t)r * 256 + k0 + ((kc ^ ((r >> 1) & 3)) << 3),
              (char*)(&sB[buf][0]) + (p * 256 + w * 64) * 16);
    }
  };

  stage(0, 0);
  stage(1, 1);
  for (int ks = 0; ks < 8; ++ks){
    const int cur = ks & 1;
    if (ks < 7) { VM_WAIT(6); } else { VM_WAIT(0); }   // slice ks retired; ks+1 in flight
    SBAR();
    bf8 af[4], bfv[8];
#pragma unroll
    for (int mi = 0; mi < 4; ++mi)
      af[mi] = *(const bf8*)((const char*)(&sA[cur][0]) + (wr * 64 + mi * 16 + lm) * 64 + swz);
#pragma unroll
    for (int ni = 0; ni < 8; ++ni)
      bfv[ni] = *(const bf8*)((const char*)(&sB[cur][0]) + (wc * 128 + ni * 16 + lm) * 64 + swz);
#pragma unroll
    for (int mi = 0; mi < 4; ++mi)
#pragma unroll
      for (int ni = 0; ni < 8; ++ni)
        acc[mi][ni] = __builtin_amdgcn_mfma_f32_16x16x32_bf16(bfv[ni], af[mi], acc[mi][ni], 0, 0, 0);
    SBAR();                               // all waves done reading b[cur]
    if (ks < 6) stage(ks + 2, cur);       // overwrite the freed buffer
  }

#pragma unroll
  for (int ni = 0; ni < 8; ++ni){
    const int ob = wc * 128 + ni * 16 + lk * 4;
    const float4 b4 = *(const float4*)(bias + ob);
#pragma unroll
    for (int mi = 0; mi < 4; ++mi){
      const int px = wr * 64 + mi * 16 + lm;
      s4v o4;
#pragma unroll
      for (int j = 0; j < 4; ++j){
        float v = acc[mi][ni][j] + ((const float*)&b4)[j];
        if (ACT == 1) v = act_gelu(v);
        else if (ACT == 2) v = act_softplus(v);
        o4[j] = f2bf(v);
      }
      *(s4v*)(outp + (m0 + px) * 256 + ob) = o4;
    }
  }
}

// -------- fused chain: out = softplus(gelu(xn*W1+b1)*W2+b2), 64-px tile, 256 thr --------
// Both passes counted-vmcnt pipelined; W2 slices 0,1 pre-staged under the h1 epilogue and
// carried ACROSS the pass boundary (lgkmcnt(0)+s_barrier only — no vmcnt drain).
__global__ __launch_bounds__(256, 2)
void k_chain(const short* __restrict__ A, const short* __restrict__ W1, const float* __restrict__ b1,
             const short* __restrict__ W2, const float* __restrict__ b2, short* __restrict__ out){
  __shared__ short sA[2][64 * 32];    // 4KB x2
  __shared__ short sB[2][256 * 32];   // 16KB x2
  __shared__ short h1[64 * 256];      // 32KB, 512B rows, 16B-slot XOR layout
  const int t = threadIdx.x, l = t & 63, w = t >> 6;
  const int lm = l & 15, lk = l >> 4;
  const size_t m0 = (size_t)blockIdx.x * 64;
  const int swz = ((lk ^ ((lm >> 1) & 3)) << 4);
  f32x4 acc[4][4] = {};

  auto stageA = [&](int ks, int buf){       // 1 vmem instr
    const int r = t >> 2, kc = t & 3;
    gload16(A + (m0 + r) * 256 + ks * 32 + ((kc ^ ((r >> 1) & 3)) << 3),
            (char*)(&sA[buf][0]) + w * 1024);
  };
  auto stageW = [&](const short* Wm, int ks, int buf){   // 4 vmem instr
#pragma unroll
    for (int p = 0; p < 4; ++p){
      const int q = p * 256 + t, r = q >> 2, kc = q & 3;
      gload16(Wm + (size_t)r * 256 + ks * 32 + ((kc ^ ((r >> 1) & 3)) << 3),
              (char*)(&sB[buf][0]) + (p * 256 + w * 64) * 16);
    }
  };

  // ---- pass 1: h1 = gelu(A*W1 + b1), 5 loads/slice -> vmcnt(5) ----
  stageA(0, 0); stageW(W1, 0, 0);
  stageA(1, 1); stageW(W1, 1, 1);
  for (int ks = 0; ks < 8; ++ks){
    const int cur = ks & 1;
    if (ks < 7) { VM_WAIT(5); } else { VM_WAIT(0); }
    SBAR();
    bf8 af[4], bfv[4];
#pragma unroll
    for (int mi = 0; mi < 4; ++mi)
      af[mi] = *(const bf8*)((const char*)(&sA[cur][0]) + (mi * 16 + lm) * 64 + swz);
#pragma unroll
    for (int ni = 0; ni < 4; ++ni)
      bfv[ni] = *(const bf8*)((const char*)(&sB[cur][0]) + (w * 64 + ni * 16 + lm) * 64 + swz);
#pragma unroll
    for (int mi = 0; mi < 4; ++mi)
#pragma unroll
      for (int ni = 0; ni < 4; ++ni)
        acc[mi][ni] = __builtin_amdgcn_mfma_f32_16x16x32_bf16(bfv[ni], af[mi], acc[mi][ni], 0, 0, 0);
    SBAR();
    if (ks < 6){ stageA(ks + 2, cur); stageW(W1, ks + 2, cur); }
  }

  // h1 epilogue (bias loads precede W2 pre-stages -> they drain first in vmcnt order)
#pragma unroll
  for (int ni = 0; ni < 4; ++ni){
    const int ob = w * 64 + ni * 16 + lk * 4;        // 4 consecutive h1 channels
    const float4 b4 = *(const float4*)(b1 + ob);
#pragma unroll
    for (int mi = 0; mi < 4; ++mi){
      const int px = mi * 16 + lm;
      s4v o4;
#pragma unroll
      for (int j = 0; j < 4; ++j)
        o4[j] = f2bf(act_gelu(acc[mi][ni][j] + ((const float*)&b4)[j]));
      const int slot = (ob >> 3) ^ (px & 7);
      *(s4v*)((char*)h1 + px * 512 + (slot << 4) + (ob & 4) * 2) = o4;
      acc[mi][ni] = (f32x4){0.f, 0.f, 0.f, 0.f};
    }
  }
  stageW(W2, 0, 0); stageW(W2, 1, 1);   // fly across the boundary barrier
  LGKM0();                              // h1 ds_writes visible (vmcnt NOT drained)

  // ---- pass 2: out = softplus(h1*W2 + b2), 4 loads/slice -> vmcnt(4) ----
  for (int ks = 0; ks < 8; ++ks){
    const int cur = ks & 1;
    if (ks < 7) { VM_WAIT(4); } else { VM_WAIT(0); }
    SBAR();
    bf8 af[4], bfv[4];
#pragma unroll
    for (int mi = 0; mi < 4; ++mi){
      const int row = mi * 16 + lm;
      const int slot = (ks * 4 + lk) ^ (row & 7);
      af[mi] = *(const bf8*)((const char*)h1 + row * 512 + (slot << 4));
    }
#pragma unroll
    for (int ni = 0; ni < 4; ++ni)
      bfv[ni] = *(const bf8*)((const char*)(&sB[cur][0]) + (w * 64 + ni * 16 + lm) * 64 + swz);
#pragma unroll
    for (int mi = 0; mi < 4; ++mi)
#pragma unroll
      for (int ni = 0; ni < 4; ++ni)
        acc[mi][ni] = __builtin_amdgcn_mfma_f32_16x16x32_bf16(bfv[ni], af[mi], acc[mi][ni], 0, 0, 0);
    SBAR();
    if (ks < 6) stageW(W2, ks + 2, cur);
  }
#pragma unroll
  for (int ni = 0; ni < 4; ++ni){
    const int ob = w * 64 + ni * 16 + lk * 4;
    const float4 b4 = *(const float4*)(b2 + ob);
#pragma unroll
    for (int mi = 0; mi < 4; ++mi){
      const int px = mi * 16 + lm;
      s4v o4;
#pragma unroll
      for (int j = 0; j < 4; ++j)
        o4[j] = f2bf(act_softplus(acc[mi][ni][j] + ((const float*)&b4)[j]));
      *(s4v*)(out + (m0 + px) * 256 + ob) = o4;
    }
  }
}

// ---------- kv partials: kv[c][d] = sum_n K[c][n]*V[d][n], n split 8-way; + ksum ----------
__global__ __launch_bounds__(256) void k_kv(const short* __restrict__ kg, const short* __restrict__ vg,
                                            float* __restrict__ kvpart, float* __restrict__ kspart){
  const int s = blockIdx.x, h = blockIdx.y, b = blockIdx.z;
  __shared__ short sk[64 * 72], sv[64 * 72];
  __shared__ float pl[256][8];
  const int t = threadIdx.x, l = t & 63, w = t >> 6;
  const int lm = l & 15, lk = l >> 4;
  float ksp[8];
#pragma unroll
  for (int j = 0; j < 8; ++j) ksp[j] = 0.f;
  f32x4 acc[4] = {};
  const size_t rowbase = ((size_t)b * 16384 + s * 2048) * 256 + h * 64;

  for (int tt = 0; tt < 32; ++tt){
    __syncthreads();
#pragma unroll
    for (int p = 0; p < 2; ++p){
      const int q = p * 256 + t;
      const int nl = q >> 3, c8 = (q & 7) * 8;
      bf8 kvv = *(const bf8*)(kg + rowbase + (size_t)(tt * 64 + nl) * 256 + c8);
      bf8 vvv = *(const bf8*)(vg + rowbase + (size_t)(tt * 64 + nl) * 256 + c8);
#pragma unroll
      for (int j = 0; j < 8; ++j){
        sk[(c8 + j) * 72 + nl] = kvv[j];
        sv[(c8 + j) * 72 + nl] = vvv[j];
        ksp[j] += bf2f(kvv[j]);
      }
    }
    __syncthreads();
#pragma unroll
    for (int ks = 0; ks < 2; ++ks){
      bf8 ak = *(const bf8*)((const char*)sk + (w * 16 + lm) * 144 + ks * 64 + lk * 16);
#pragma unroll
      for (int ni = 0; ni < 4; ++ni){
        bf8 bv = *(const bf8*)((const char*)sv + (ni * 16 + lm) * 144 + ks * 64 + lk * 16);
        acc[ni] = __builtin_amdgcn_mfma_f32_16x16x32_bf16(ak, bv, acc[ni], 0, 0, 0);
      }
    }
  }
#pragma unroll
  for (int j = 0; j < 8; ++j) pl[t][j] = ksp[j];
  __syncthreads();
  const size_t slot = (size_t)(b * 4 + h) * 8 + s;
  if (t < 64){
    float sum = 0.f;
    const int g8 = t >> 3, j = t & 7;
    for (int m = 0; m < 32; ++m) sum += pl[m * 8 + g8][j];
    kspart[slot * 64 + t] = sum;
  }
  float* kvp = kvpart + slot * 4096;
#pragma unroll
  for (int ni = 0; ni < 4; ++ni)
#pragma unroll
    for (int j = 0; j < 4; ++j){
      const int c = w * 16 + lk * 4 + j, d = ni * 16 + lm;
      kvp[c * 64 + d] = acc[ni][j];
    }
}

// ---------- reduce partials -> kvT (b,h,d,c) bf16 (scale folded) + ksum fp32 ----------
__global__ __launch_bounds__(256) void k_kvred(const float* __restrict__ kvpart, const float* __restrict__ kspart,
                                               short* __restrict__ kvT, float* __restrict__ ksum_s){
  const int gid = blockIdx.x * 256 + threadIdx.x;
#pragma unroll
  for (int i = 0; i < 8; ++i){
    const int o = gid * 8 + i;
    const int bh = o >> 12, rem = o & 4095, d = rem >> 6, c = rem & 63;
    float sum = 0.f;
#pragma unroll
    for (int s = 0; s < 8; ++s) sum += kvpart[((size_t)bh * 8 + s) * 4096 + c * 64 + d];
    kvT[o] = f2bf(sum * 0.125f);
  }
  if (gid < 2048){
    float sum = 0.f;
#pragma unroll
    for (int s = 0; s < 8; ++s) sum += kspart[((size_t)(gid >> 6) * 8 + s) * 64 + (gid & 63)];
    ksum_s[gid] = sum * 0.125f;
  }
}

// ---------- FUSED: g-GEMM + attention finalize + final conv, 64-px tile, 256 thr ----------
// Phase 1: g = gelu(xn*Wg+bg) (swapped, counted-vmcnt) -> kept in registers.
// Phase 2: z-dot + PV + y -> LDS (slot-XOR); Wo slices 0,1 pre-staged under the epilogue
// and carried across the boundary (lgkm-only barrier). Phase 3: y*Wo+bo -> fp32 CHW.
__global__ __launch_bounds__(256, 2)
void k_fuse(const short* __restrict__ xn, const short* __restrict__ qg,
            const short* __restrict__ vg, const short* __restrict__ kvT,
            const float* __restrict__ ksum_s,
            const short* __restrict__ Wg, const float* __restrict__ bg,
            const short* __restrict__ Wo, const float* __restrict__ bo,
            float* __restrict__ outp){
  __shared__ short sA[2][64 * 32];    // 4KB x2 (xn staging)
  __shared__ short sB[2][256 * 32];   // 16KB x2 (Wg then Wo staging)
  __shared__ short yl[64 * 256];      // 32KB, 512B rows, 16B-slot XOR layout
  __shared__ float sz[256];
  __shared__ float sks[256];
  const int t = threadIdx.x, l = t & 63, w = t >> 6;
  const int lm = l & 15, lk = l >> 4;
  const size_t m0 = (size_t)blockIdx.x * 64;
  const int b = (int)(m0 >> 14);
  const int h = w;                    // wave == head
  const int swz = ((lk ^ ((lm >> 1) & 3)) << 4);

  sks[t] = ksum_s[b * 256 + t];       // issued FIRST: oldest vmem op, drains first

  auto stageA = [&](int ks, int buf){       // 1 vmem instr
    const int r = t >> 2, kc = t & 3;
    gload16(xn + (m0 + r) * 256 + ks * 32 + ((kc ^ ((r >> 1) & 3)) << 3),
            (char*)(&sA[buf][0]) + w * 1024);
  };
  auto stageW = [&](const short* Wm, int ks, int buf){   // 4 vmem instr
#pragma unroll
    for (int p = 0; p < 4; ++p){
      const int q = p * 256 + t, r = q >> 2, kc = q & 3;
      gload16(Wm + (size_t)r * 256 + ks * 32 + ((kc ^ ((r >> 1) & 3)) << 3),
              (char*)(&sB[buf][0]) + (p * 256 + w * 64) * 16);
    }
  };

  f32x4 acc[4][4] = {};

  // ---- phase 1: g = gelu(xn*Wg + bg), swapped, 5 loads/slice -> vmcnt(5) ----
  stageA(0, 0); stageW(Wg, 0, 0);
  stageA(1, 1); stageW(Wg, 1, 1);
  for (int ks = 0; ks < 8; ++ks){
    const int cur = ks & 1;
    if (ks < 7) { VM_WAIT(5); } else { VM_WAIT(0); }   // iter0 also drains the sks load
    SBAR();
    bf8 af[4], bfv[4];
#pragma unroll
    for (int mi = 0; mi < 4; ++mi)
      af[mi] = *(const bf8*)((const char*)(&sA[cur][0]) + (mi * 16 + lm) * 64 + swz);
#pragma unroll
    for (int ni = 0; ni < 4; ++ni)
      bfv[ni] = *(const bf8*)((const char*)(&sB[cur][0]) + (w * 64 + ni * 16 + lm) * 64 + swz);
#pragma unroll
    for (int mi = 0; mi < 4; ++mi)
#pragma unroll
      for (int ni = 0; ni < 4; ++ni)
        acc[mi][ni] = __builtin_amdgcn_mfma_f32_16x16x32_bf16(bfv[ni], af[mi], acc[mi][ni], 0, 0, 0);
    SBAR();
    if (ks < 6){ stageA(ks + 2, cur); stageW(Wg, ks + 2, cur); }
  }
  s4v g_pk[4][4];                     // g as packed bf16, 32 VGPRs
#pragma unroll
  for (int ni = 0; ni < 4; ++ni){
    const int ob = h * 64 + ni * 16 + lk * 4;
    const float4 b4 = *(const float4*)(bg + ob);
#pragma unroll
    for (int mi = 0; mi < 4; ++mi){
#pragma unroll
      for (int j = 0; j < 4; ++j)
        g_pk[mi][ni][j] = f2bf(act_gelu(acc[mi][ni][j] + ((const float*)&b4)[j]));
      acc[mi][ni] = (f32x4){0.f, 0.f, 0.f, 0.f};
    }
  }

  // ---- z = 1/(q . ksum + n): lane = pixel, wave = head ----
  {
    float dot = 0.f;
#pragma unroll
    for (int cc = 0; cc < 8; ++cc){
      bf8 qv = *(const bf8*)(qg + (m0 + l) * 256 + h * 64 + cc * 8);
#pragma unroll
      for (int j = 0; j < 8; ++j) dot += bf2f(qv[j]) * sks[h * 64 + cc * 8 + j];
    }
    sz[h * 64 + l] = 1.0f / (dot + 16384.0f);
  }

  // ---- phase 2: PV (swapped) + y epilogue into LDS ----
  const short* kvb = kvT + (size_t)b * 16384;
#pragma unroll
  for (int ks = 0; ks < 2; ++ks){
    bf8 aq[4];
#pragma unroll
    for (int mi = 0; mi < 4; ++mi)
      aq[mi] = *(const bf8*)(qg + (m0 + mi * 16 + lm) * 256 + h * 64 + ks * 32 + lk * 8);
#pragma unroll
    for (int ni = 0; ni < 4; ++ni){
      bf8 bk = *(const bf8*)(kvb + (size_t)(h * 64 + ni * 16 + lm) * 64 + ks * 32 + lk * 8);
#pragma unroll
      for (int mi = 0; mi < 4; ++mi)
        acc[mi][ni] = __builtin_amdgcn_mfma_f32_16x16x32_bf16(bk, aq[mi], acc[mi][ni], 0, 0, 0);
    }
  }
#pragma unroll
  for (int mi = 0; mi < 4; ++mi){
    const int px = mi * 16 + lm;
    const float zf = sz[h * 64 + px];        // own wave's writes
    const size_t base = (m0 + px) * 256;
#pragma unroll
    for (int ni = 0; ni < 4; ++ni){
      const int ch = h * 64 + ni * 16 + lk * 4;
      s4v v4 = *(const s4v*)(vg + base + ch);
      s4v o4;
#pragma unroll
      for (int j = 0; j < 4; ++j)
        o4[j] = f2bf((acc[mi][ni][j] + bf2f(v4[j])) * zf * bf2f(g_pk[mi][ni][j]));
      const int slot = (ch >> 3) ^ (px & 7);
      *(s4v*)((char*)yl + px * 512 + (slot << 4) + (ch & 4) * 2) = o4;
      acc[mi][ni] = (f32x4){0.f, 0.f, 0.f, 0.f};
    }
  }
  stageW(Wo, 0, 0); stageW(Wo, 1, 1);   // fly across the boundary barrier
  LGKM0();                              // yl ds_writes visible (vmcnt NOT drained)

  // ---- phase 3: out = y*Wo + bo (UNSWAPPED), 4 loads/slice -> vmcnt(4) ----
  for (int ks = 0; ks < 8; ++ks){
    const int cur = ks & 1;
    if (ks < 7) { VM_WAIT(4); } else { VM_WAIT(0); }
    SBAR();
    bf8 af[4], bfv[4];
#pragma unroll
    for (int mi = 0; mi < 4; ++mi){
      const int row = mi * 16 + lm;
      const int slot = (ks * 4 + lk) ^ (row & 7);
      af[mi] = *(const bf8*)((const char*)yl + row * 512 + (slot << 4));
    }
#pragma unroll
    for (int ni = 0; ni < 4; ++ni)
      bfv[ni] = *(const bf8*)((const char*)(&sB[cur][0]) + (w * 64 + ni * 16 + lm) * 64 + swz);
#pragma unroll
    for (int mi = 0; mi < 4; ++mi)
#pragma unroll
      for (int ni = 0; ni < 4; ++ni)
        acc[mi][ni] = __builtin_amdgcn_mfma_f32_16x16x32_bf16(af[mi], bfv[ni], acc[mi][ni], 0, 0, 0);
    SBAR();
    if (ks < 6) stageW(Wo, ks + 2, cur);
  }
  const int nb = (int)(m0 & 16383);
#pragma unroll
  for (int mi = 0; mi < 4; ++mi){
    const int np = nb + mi * 16 + lk * 4;    // 4 consecutive pixels via f32x4 lanes
#pragma unroll
    for (int ni = 0; ni < 4; ++ni){
      const int o = w * 64 + ni * 16 + lm;
      const float bi = bo[o];
      float4 v;
      v.x = acc[mi][ni][0] + bi; v.y = acc[mi][ni][1] + bi;
      v.z = acc[mi][ni][2] + bi; v.w = acc[mi][ni][3] + bi;
      *(float4*)(outp + (((size_t)(b * 256 + o)) * 16384 + np)) = v;
    }
  }
}

extern "C" void kernel_launch(void* const* d_in, const int* in_sizes, int n_in,
                              void* d_out, int out_size, void* d_ws, size_t ws_size,
                              hipStream_t stream){
  (void)in_sizes; (void)n_in; (void)out_size; (void)ws_size;
  const float* x   = (const float*)d_in[0];
  const float* wq1 = (const float*)d_in[1];
  const float* bq1 = (const float*)d_in[2];
  const float* wq2 = (const float*)d_in[3];
  const float* bq2 = (const float*)d_in[4];
  const float* wk1 = (const float*)d_in[5];
  const float* bk1 = (const float*)d_in[6];
  const float* wk2 = (const float*)d_in[7];
  const float* bk2 = (const float*)d_in[8];
  const float* wv  = (const float*)d_in[9];
  const float* bv  = (const float*)d_in[10];
  const float* wg  = (const float*)d_in[11];
  const float* bg  = (const float*)d_in[12];
  const float* wo  = (const float*)d_in[13];
  const float* bo  = (const float*)d_in[14];

  char* ws = (char*)d_ws;
  float* mu     = (float*)(ws + 0);
  float* rsig   = (float*)(ws + 8192);
  short* wb     = (short*)(ws + 16384);            // 7 x 65536 bf16
  float* kvpart = (float*)(ws + 933888);           // (b,h,s,c,d) partials, 4MB
  float* ps1    = (float*)(ws + 933888);           // 2MB (dead before k_kv runs)
  float* ps2    = (float*)(ws + 3031040);          // 2MB
  float* kspart = (float*)(ws + 5128192);
  short* kvT    = (short*)(ws + 5193728);
  float* ksum_s = (float*)(ws + 5455872);
  short* B0 = (short*)(ws + 8388608);              // xt -> xn
  short* B1 = B0 + 33554432;                       // v
  short* B2 = B1 + 33554432;                       // q
  short* B3 = B2 + 33554432;                       // k

  k_wconv<<<448, 256, 0, stream>>>(wq1, wq2, wk1, wk2, wv, wg, wo, wb);
  k_statst<<<dim3(256, 4, 8), 256, 0, stream>>>(x, B0, ps1, ps2);   // xt + partials
  k_red<<<2048, 256, 0, stream>>>(ps1, ps2, mu, rsig);
  k_norm<<<2048, 256, 0, stream>>>(B0, mu, rsig);                   // in-place xt -> xn
  k_chain<<<2048, 256, 0, stream>>>(B0, wb + 0 * 65536, bq1, wb + 1 * 65536, bq2, B2); // q
  k_chain<<<2048, 256, 0, stream>>>(B0, wb + 2 * 65536, bk1, wb + 3 * 65536, bk2, B3); // k
  k_gemm0<1><<<1024, 256, 0, stream>>>(B0, wb + 4 * 65536, bv, B1);     // v = gelu
  k_kv<<<dim3(8, 4, 8), 256, 0, stream>>>(B3, B1, kvpart, kspart);
  k_kvred<<<64, 256, 0, stream>>>(kvpart, kspart, kvT, ksum_s);
  k_fuse<<<2048, 256, 0, stream>>>(B0, B2, B1, kvT, ksum_s,
                                   wb + 5 * 65536, bg, wb + 6 * 65536, bo,
                                   (float*)d_out);                      // g+attn+final
}